// Round 14
// baseline (25.282 us; speedup 1.0000x reference)
//
#include <hip/hip_runtime.h>
#include <math.h>

// B=4, K=256, D=128, H=4, alpha=0.2
// leaky(s) = 0.6*s + 0.4*|s|  (exact for alpha=0.2)
// e_ij = [0.6*(a.Lp_i) cancels in softmax] + 0.6*(a.R_j) + sum_d (0.4 a_d)|Lp_id + R_jd| + bias_ij
// mean_h(P_h @ x) = (mean_h P_h) @ x.
// k1: f16-pair dot2 GEMM -> Lpp/Rtp packed f16 + eb (j-only softmax term).  (R12/R13, unchanged)
// k2: 512-thr blocks, wave = (head, j-half); thread owns 2j x 2i over full d.
//     Cross-wave softmax combine via 32-float LDS; P-bar fp32 LDS; single PV -> out.
constexpr int Kc = 256, Dc = 128, Mc = 1024;    // Mc = B*K

typedef _Float16 h2_t __attribute__((ext_vector_type(2)));
union U32H2 { unsigned int u; h2_t h; };
__device__ inline h2_t u2h(unsigned int u) { U32H2 x; x.u = u; return x.h; }
__device__ inline unsigned int h2u(h2_t h) { U32H2 x; x.h = h; return x.u; }
__device__ inline unsigned int packh(float a, float b) {
    h2_t h; h.x = (_Float16)a; h.y = (_Float16)b; return h2u(h);
}

#if __has_builtin(__builtin_amdgcn_fdot2)
__device__ inline float dot2h(unsigned int a, unsigned int b, float c) {
    return __builtin_amdgcn_fdot2(u2h(a), u2h(b), c, false);
}
#else
__device__ inline float dot2h(unsigned int a, unsigned int b, float c) {
    h2_t ah = u2h(a), bh = u2h(b);
    return fmaf((float)ah.x, (float)bh.x, fmaf((float)ah.y, (float)bh.y, c));
}
#endif

// acc += (0.4a_2d)|l_2d + r_2d| + (0.4a_2d+1)|l_2d+1 + r_2d+1|, f32 accumulate
__device__ inline float estep(unsigned int r, unsigned int l, h2_t av, float acc) {
    h2_t s = u2h(r) + u2h(l);                       // v_pk_add_f16
    unsigned int t = h2u(s) & 0x7FFF7FFFu;          // packed abs
#if __has_builtin(__builtin_amdgcn_fdot2)
    return __builtin_amdgcn_fdot2(u2h(t), av, acc, false);   // v_dot2_f32_f16
#else
    h2_t th = u2h(t);
    return fmaf((float)th.x, (float)av.x, fmaf((float)th.y, (float)av.y, acc));
#endif
}

// ---------------------------------------------------------------------------
// K1 (256 blocks, 256 thr): 64x64-tile GEMM, 4x4 acc, f16-pair dot2 inner loop.
// (byte-identical to R12/R13)
// ---------------------------------------------------------------------------
__global__ __launch_bounds__(256) void k1(const float* __restrict__ x,
                                          const float* __restrict__ W,
                                          const float* __restrict__ lin_b,
                                          const float* __restrict__ a,
                                          unsigned int* __restrict__ Lpp,
                                          unsigned int* __restrict__ Rtp,
                                          float* __restrict__ eb) {
    __shared__ unsigned int As2[64 * 64];   // [k2][m-role] packed k-pairs, 16 KB
    __shared__ unsigned int Bs2[64 * 64];   // [k2][n-role] packed k-pairs, 16 KB
    __shared__ float red[4][16][4];

    const int tid = threadIdx.x;
    const int bid = blockIdx.x;
    const int tx = tid & 15, ty = tid >> 4;   // ty 0..15
    const bool isL = (bid < 128);

    int h, b, m0, n0, dt;
    if (isL) {
        const int nt = bid & 1, mt = (bid >> 1) & 15;
        h = (bid >> 5) & 3; b = 0; dt = 0;
        m0 = mt * 64; n0 = nt * 64;
        {
            const int m_l = tid & 63, kq = tid >> 6;
            #pragma unroll
            for (int c = 0; c < 8; ++c) {
                const float4 v = *(const float4*)&x[(m0 + m_l) * Dc + kq * 32 + c * 4];
                As2[(kq * 16 + c * 2 + 0) * 64 + m_l] = packh(v.x, v.y);
                As2[(kq * 16 + c * 2 + 1) * 64 + m_l] = packh(v.z, v.w);
            }
        }
        {
            const int n_l = tid & 63, kq = tid >> 6;
            const float* Wb = W + (h * 2) * Dc * Dc;
            #pragma unroll
            for (int kk = 0; kk < 16; ++kk) {
                const int k2 = kq * 16 + kk;
                Bs2[k2 * 64 + n_l] =
                    packh(Wb[(2 * k2) * Dc + n0 + n_l], Wb[(2 * k2 + 1) * Dc + n0 + n_l]);
            }
        }
    } else {
        const int r_ = bid - 128;
        const int jt = r_ & 3;
        dt = (r_ >> 2) & 1;
        b  = (r_ >> 3) & 3;
        h  = (r_ >> 5) & 3;
        m0 = dt * 64;          // m-role = d
        n0 = jt * 64;          // n-role = j
        {
            const int d_l = tid & 63, kq = tid >> 6;
            const float* Wb = W + ((h * 2 + 1) * Dc) * Dc;
            #pragma unroll
            for (int kk = 0; kk < 16; ++kk) {
                const int k2 = kq * 16 + kk;
                As2[k2 * 64 + d_l] =
                    packh(Wb[(2 * k2) * Dc + m0 + d_l], Wb[(2 * k2 + 1) * Dc + m0 + d_l]);
            }
        }
        {
            const int j_l = tid & 63, kq = tid >> 6;
            #pragma unroll
            for (int c = 0; c < 8; ++c) {
                const float4 v = *(const float4*)&x[(b * Kc + n0 + j_l) * Dc + kq * 32 + c * 4];
                Bs2[(kq * 16 + c * 2 + 0) * 64 + j_l] = packh(v.x, v.y);
                Bs2[(kq * 16 + c * 2 + 1) * 64 + j_l] = packh(v.z, v.w);
            }
        }
    }
    __syncthreads();

    float acc[4][4];
    #pragma unroll
    for (int r = 0; r < 4; ++r)
        #pragma unroll
        for (int c = 0; c < 4; ++c) acc[r][c] = 0.f;

    #pragma unroll 8
    for (int k2 = 0; k2 < 64; ++k2) {
        const uint4 xa = *(const uint4*)&As2[k2 * 64 + ty * 4];   // 4 m x k-pair
        const uint4 wb = *(const uint4*)&Bs2[k2 * 64 + tx * 4];   // 4 n x k-pair
        acc[0][0] = dot2h(xa.x, wb.x, acc[0][0]);
        acc[0][1] = dot2h(xa.x, wb.y, acc[0][1]);
        acc[0][2] = dot2h(xa.x, wb.z, acc[0][2]);
        acc[0][3] = dot2h(xa.x, wb.w, acc[0][3]);
        acc[1][0] = dot2h(xa.y, wb.x, acc[1][0]);
        acc[1][1] = dot2h(xa.y, wb.y, acc[1][1]);
        acc[1][2] = dot2h(xa.y, wb.z, acc[1][2]);
        acc[1][3] = dot2h(xa.y, wb.w, acc[1][3]);
        acc[2][0] = dot2h(xa.z, wb.x, acc[2][0]);
        acc[2][1] = dot2h(xa.z, wb.y, acc[2][1]);
        acc[2][2] = dot2h(xa.z, wb.z, acc[2][2]);
        acc[2][3] = dot2h(xa.z, wb.w, acc[2][3]);
        acc[3][0] = dot2h(xa.w, wb.x, acc[3][0]);
        acc[3][1] = dot2h(xa.w, wb.y, acc[3][1]);
        acc[3][2] = dot2h(xa.w, wb.z, acc[3][2]);
        acc[3][3] = dot2h(xa.w, wb.w, acc[3][3]);
    }

    if (isL) {
        const float4 lv = *(const float4*)&lin_b[h * Dc + n0 + tx * 4];
        #pragma unroll
        for (int r = 0; r < 4; ++r) {
            uint2 pk;
            pk.x = packh(acc[r][0] + lv.x, acc[r][1] + lv.y);
            pk.y = packh(acc[r][2] + lv.z, acc[r][3] + lv.w);
            *(uint2*)&Lpp[(h * Mc + m0 + ty * 4 + r) * 64 + (n0 >> 1) + tx * 2] = pk;
        }
    } else {
        #pragma unroll
        for (int rp = 0; rp < 2; ++rp) {
            uint4 pk;
            pk.x = packh(acc[2 * rp][0], acc[2 * rp + 1][0]);
            pk.y = packh(acc[2 * rp][1], acc[2 * rp + 1][1]);
            pk.z = packh(acc[2 * rp][2], acc[2 * rp + 1][2]);
            pk.w = packh(acc[2 * rp][3], acc[2 * rp + 1][3]);
            *(uint4*)&Rtp[((h * 4 + b) * 64 + (m0 >> 1) + ty * 2 + rp) * Kc + n0 + tx * 4] = pk;
        }
        const float4 av = *(const float4*)&a[h * Dc + m0 + ty * 4];
        float p0 = 0.4f * (av.x * acc[0][0] + av.y * acc[1][0] + av.z * acc[2][0] + av.w * acc[3][0]);
        float p1 = 0.4f * (av.x * acc[0][1] + av.y * acc[1][1] + av.z * acc[2][1] + av.w * acc[3][1]);
        float p2 = 0.4f * (av.x * acc[0][2] + av.y * acc[1][2] + av.z * acc[2][2] + av.w * acc[3][2]);
        float p3 = 0.4f * (av.x * acc[0][3] + av.y * acc[1][3] + av.z * acc[2][3] + av.w * acc[3][3]);
        p0 += __shfl_xor(p0, 16, 64); p0 += __shfl_xor(p0, 32, 64);
        p1 += __shfl_xor(p1, 16, 64); p1 += __shfl_xor(p1, 32, 64);
        p2 += __shfl_xor(p2, 16, 64); p2 += __shfl_xor(p2, 32, 64);
        p3 += __shfl_xor(p3, 16, 64); p3 += __shfl_xor(p3, 32, 64);
        if (((tid >> 4) & 3) == 0) {
            const int w = tid >> 6;
            red[w][tx][0] = p0; red[w][tx][1] = p1;
            red[w][tx][2] = p2; red[w][tx][3] = p3;
        }
        __syncthreads();
        if (tid < 64) {
            const int txl = tid >> 2, c = tid & 3;
            const float v = red[0][txl][c] + red[1][txl][c] + red[2][txl][c] + red[3][txl][c];
            eb[((h * 4 + b) * 2 + dt) * Kc + n0 + tid] = 1.5f * v;
        }
    }
}

// ---------------------------------------------------------------------------
// K2 (512 blocks = (b, 128 i-tiles of 2 rows), 512 thr = 8 waves, 2 blk/CU =
// 16 waves/CU, b pinned per XCD): wave w = (head w>>1, j-half w&1); thread
// owns e[2i][2j] over the FULL d=128.  Cross-wave softmax combine (max,sum)
// via 32-float LDS.  P-bar fp32 in LDS -> single PV (16-way jq) -> out.
// ---------------------------------------------------------------------------
__global__ __launch_bounds__(512) void k2(const float* __restrict__ x,
                                          const float* __restrict__ a,
                                          const float* __restrict__ bias,
                                          const unsigned int* __restrict__ Lpp,
                                          const unsigned int* __restrict__ Rtp,
                                          const float* __restrict__ eb,
                                          float* __restrict__ out) {
    __shared__ float red[512 * 12];           // 24 KB PV reduce scratch
    __shared__ unsigned int lpT2[4 * 64 * 2]; // [h][dp][i] 2 KB packed-f16 Lp
    __shared__ unsigned int aa2s[4 * 64];     // [h][dp] packed-f16 0.4*a pairs 1 KB
    __shared__ float pP[8 * Kc];              // [(h,row)][j] 0.25*P, 8 KB
    __shared__ float plbar[2 * Kc];           // fp32 P-bar 2 KB
    __shared__ float smx[8][2];               // per-wave row max
    __shared__ float ssm[8][2];               // per-wave row sum

    const int tid = threadIdx.x;
    const int L = blockIdx.x;
    // XCD-pin: L&7 -> XCD; b = xcd>>1 (2 XCDs per b); it from remaining bits.
    const int xcd = L & 7;
    const int b = xcd >> 1;
    const int it = ((L >> 3) << 1) | (xcd & 1);   // 0..127
    const int i0 = it * 2;

    if (tid < 256) {   // stage lpT2[h][dp][i] + aa2s
        const int hs = tid >> 6, dp = tid & 63;
        uint2 v;
        v.x = Lpp[(hs * Mc + b * Kc + i0 + 0) * 64 + dp];
        v.y = Lpp[(hs * Mc + b * Kc + i0 + 1) * 64 + dp];
        *(uint2*)&lpT2[(hs * 64 + dp) * 2] = v;
        aa2s[tid] = packh(0.4f * a[hs * Dc + 2 * dp], 0.4f * a[hs * Dc + 2 * dp + 1]);
    }
    __syncthreads();

    const int w = tid >> 6;                   // wave 0..7
    const int h = w >> 1, jh = w & 1, l = tid & 63;
    const int hb = h * 4 + b;
    const int jb = jh * 128 + l * 2;          // j-pair base

    // hoisted epilogue loads (latency overlaps e-loop)
    const float2 ebs0 = *(const float2*)&eb[(hb * 2 + 0) * Kc + jb];
    const float2 ebs1 = *(const float2*)&eb[(hb * 2 + 1) * Kc + jb];
    const float2 bv0  = *(const float2*)&bias[(h * Kc + i0 + 0) * Kc + jb];
    const float2 bv1  = *(const float2*)&bias[(h * Kc + i0 + 1) * Kc + jb];

    // ---- e-phase: full d in-thread, e[2 rows][2 j] ----
    float a0x = 0.f, a0y = 0.f, a1x = 0.f, a1y = 0.f;
    {
        const unsigned int* rb = Rtp + (hb * 64) * Kc + jb;
        const unsigned int* lt = lpT2 + (h * 64) * 2;
        const unsigned int* at = aa2s + h * 64;
        #pragma unroll 8
        for (int dp = 0; dp < 64; ++dp) {
            const uint2 rr = *(const uint2*)(rb + dp * Kc);    // 2 j x 2 d (global, L2-hot)
            const uint2 lp2 = *(const uint2*)(lt + dp * 2);    // 2 i x 2 d (LDS b64 broadcast)
            const h2_t av = u2h(at[dp]);                       // LDS b32 broadcast
            a0x = estep(rr.x, lp2.x, av, a0x);
            a0y = estep(rr.y, lp2.x, av, a0y);
            a1x = estep(rr.x, lp2.y, av, a1x);
            a1y = estep(rr.y, lp2.y, av, a1y);
        }
    }
    const float e0x = a0x + ebs0.x + ebs1.x + bv0.x;
    const float e0y = a0y + ebs0.y + ebs1.y + bv0.y;
    const float e1x = a1x + ebs0.x + ebs1.x + bv1.x;
    const float e1y = a1y + ebs0.y + ebs1.y + bv1.y;

    // ---- softmax: wave-local reduce + cross-wave (2 j-halves) combine ----
    {
        float m0 = fmaxf(e0x, e0y), m1 = fmaxf(e1x, e1y);
        #pragma unroll
        for (int off = 1; off < 64; off <<= 1) {
            m0 = fmaxf(m0, __shfl_xor(m0, off, 64));
            m1 = fmaxf(m1, __shfl_xor(m1, off, 64));
        }
        if (l == 0) { smx[w][0] = m0; smx[w][1] = m1; }
    }
    __syncthreads();
    const float M0 = fmaxf(smx[h * 2][0], smx[h * 2 + 1][0]);
    const float M1 = fmaxf(smx[h * 2][1], smx[h * 2 + 1][1]);
    const float p0x = __expf(e0x - M0), p0y = __expf(e0y - M0);
    const float p1x = __expf(e1x - M1), p1y = __expf(e1y - M1);
    {
        float s0 = p0x + p0y, s1 = p1x + p1y;
        #pragma unroll
        for (int off = 1; off < 64; off <<= 1) {
            s0 += __shfl_xor(s0, off, 64);
            s1 += __shfl_xor(s1, off, 64);
        }
        if (l == 0) { ssm[w][0] = s0; ssm[w][1] = s1; }
    }
    __syncthreads();
    {
        const float sc0 = 0.25f / (ssm[h * 2][0] + ssm[h * 2 + 1][0]);   // fold mean over H
        const float sc1 = 0.25f / (ssm[h * 2][1] + ssm[h * 2 + 1][1]);
        *(float2*)&pP[(h * 2 + 0) * Kc + jb] = make_float2(p0x * sc0, p0y * sc0);
        *(float2*)&pP[(h * 2 + 1) * Kc + jb] = make_float2(p1x * sc1, p1y * sc1);
    }
    __syncthreads();

    // ---- P-bar = sum over 4 heads ----
    if (tid < 128) {
        const int r = tid >> 6, c = tid & 63;
        float4 s = make_float4(0.f, 0.f, 0.f, 0.f);
        #pragma unroll
        for (int h4 = 0; h4 < 4; ++h4) {
            const float4 v = *(const float4*)&pP[(h4 * 2 + r) * Kc + c * 4];
            s.x += v.x; s.y += v.y; s.z += v.z; s.w += v.w;
        }
        *(float4*)&plbar[r * Kc + c * 4] = s;
    }
    __syncthreads();

    // ---- single PV: out[i][d] = sum_j plbar[i][j] * x[b][j][d], 16-way jq ----
    const int jq = tid >> 5, dd4 = tid & 31;
    float4 o0 = make_float4(0.f, 0.f, 0.f, 0.f);
    float4 o1 = make_float4(0.f, 0.f, 0.f, 0.f);
    {
        const float* xb = x + (b * Kc) * Dc + dd4 * 4;
        #pragma unroll 4
        for (int jj = 0; jj < 16; ++jj) {
            const int j = jj * 16 + jq;
            const float4 xv = *(const float4*)(xb + j * Dc);   // global, L2-hot
            const float pv0 = plbar[j];                         // LDS broadcast
            const float pv1 = plbar[Kc + j];
            o0.x = fmaf(pv0, xv.x, o0.x); o0.y = fmaf(pv0, xv.y, o0.y);
            o0.z = fmaf(pv0, xv.z, o0.z); o0.w = fmaf(pv0, xv.w, o0.w);
            o1.x = fmaf(pv1, xv.x, o1.x); o1.y = fmaf(pv1, xv.y, o1.y);
            o1.z = fmaf(pv1, xv.z, o1.z); o1.w = fmaf(pv1, xv.w, o1.w);
        }
    }
    {
        float* myred = red + (jq * 32 + dd4) * 12;
        *(float4*)&myred[0] = o0;
        *(float4*)&myred[4] = o1;
    }
    __syncthreads();
    if (tid < 64) {
        const int i_f = tid >> 5, dd_f = tid & 31;
        float4 s = make_float4(0.f, 0.f, 0.f, 0.f);
        #pragma unroll
        for (int q = 0; q < 16; ++q) {
            const float4 v = *(const float4*)&red[(q * 32 + dd_f) * 12 + i_f * 4];
            s.x += v.x; s.y += v.y; s.z += v.z; s.w += v.w;
        }
        *(float4*)&out[(b * Kc + i0 + i_f) * Dc + dd_f * 4] = s;
    }
}

extern "C" void kernel_launch(void* const* d_in, const int* in_sizes, int n_in,
                              void* d_out, int out_size, void* d_ws, size_t ws_size,
                              hipStream_t stream) {
    const float* x     = (const float*)d_in[0];
    const float* W     = (const float*)d_in[1];
    const float* lin_b = (const float*)d_in[2];
    const float* a     = (const float*)d_in[3];
    const float* bias  = (const float*)d_in[4];
    float* out = (float*)d_out;

    unsigned int*   Lpp = (unsigned int*)d_ws;                // f16x2 [H][M][64]   (1 MB)
    unsigned int*   Rtp = Lpp + 4 * Mc * 64;                  // f16x2 [16][64][K]  (1 MB)
    float*          eb  = (float*)(Rtp + 16 * 64 * Kc);       // fp32  [16*2][K]    (32 KB)

    k1<<<256, 256, 0, stream>>>(x, W, lin_b, a, Lpp, Rtp, eb);
    k2<<<512, 512, 0, stream>>>(x, a, bias, Lpp, Rtp, eb, out);
}

// Round 15
// 23.491 us; speedup vs baseline: 1.0762x; 1.0762x over previous
//
#include <hip/hip_runtime.h>
#include <math.h>

// B=4, K=256, D=128, H=4, alpha=0.2
// leaky(s) = 0.6*s + 0.4*|s|  (exact for alpha=0.2)
// e_ij = [0.6*(a.Lp_i) cancels in softmax] + 0.6*(a.R_j) + sum_d (0.4 a_d)|Lp_id + R_jd| + bias_ij
// mean_h(P_h @ x) = (mean_h P_h) @ x.
// k1: f16-pair dot2 GEMM -> Lpp/Rtp packed f16 + eb (j-only softmax term).
// k2 (R13 champion): wave w = head w, thread owns full d=128 for (2i x 4j);
//     no cross-thread d-reduce, 4 heads concurrent, P-bar in LDS -> single PV -> out.
//     + hoisted eb/bias loads, PV unroll 8.
constexpr int Kc = 256, Dc = 128, Mc = 1024;    // Mc = B*K

typedef _Float16 h2_t __attribute__((ext_vector_type(2)));
union U32H2 { unsigned int u; h2_t h; };
__device__ inline h2_t u2h(unsigned int u) { U32H2 x; x.u = u; return x.h; }
__device__ inline unsigned int h2u(h2_t h) { U32H2 x; x.h = h; return x.u; }
__device__ inline unsigned int packh(float a, float b) {
    h2_t h; h.x = (_Float16)a; h.y = (_Float16)b; return h2u(h);
}

#if __has_builtin(__builtin_amdgcn_fdot2)
__device__ inline float dot2h(unsigned int a, unsigned int b, float c) {
    return __builtin_amdgcn_fdot2(u2h(a), u2h(b), c, false);
}
#else
__device__ inline float dot2h(unsigned int a, unsigned int b, float c) {
    h2_t ah = u2h(a), bh = u2h(b);
    return fmaf((float)ah.x, (float)bh.x, fmaf((float)ah.y, (float)bh.y, c));
}
#endif

// acc += (0.4a_2d)|l_2d + r_2d| + (0.4a_2d+1)|l_2d+1 + r_2d+1|, f32 accumulate
__device__ inline float estep(unsigned int r, unsigned int l, h2_t av, float acc) {
    h2_t s = u2h(r) + u2h(l);                       // v_pk_add_f16
    unsigned int t = h2u(s) & 0x7FFF7FFFu;          // packed abs
#if __has_builtin(__builtin_amdgcn_fdot2)
    return __builtin_amdgcn_fdot2(u2h(t), av, acc, false);   // v_dot2_f32_f16
#else
    h2_t th = u2h(t);
    return fmaf((float)th.x, (float)av.x, fmaf((float)th.y, (float)av.y, acc));
#endif
}

// ---------------------------------------------------------------------------
// K1 (256 blocks, 256 thr): 64x64-tile GEMM, 4x4 acc, f16-pair dot2 inner loop.
// (byte-identical to R12/R13)
// ---------------------------------------------------------------------------
__global__ __launch_bounds__(256) void k1(const float* __restrict__ x,
                                          const float* __restrict__ W,
                                          const float* __restrict__ lin_b,
                                          const float* __restrict__ a,
                                          unsigned int* __restrict__ Lpp,
                                          unsigned int* __restrict__ Rtp,
                                          float* __restrict__ eb) {
    __shared__ unsigned int As2[64 * 64];   // [k2][m-role] packed k-pairs, 16 KB
    __shared__ unsigned int Bs2[64 * 64];   // [k2][n-role] packed k-pairs, 16 KB
    __shared__ float red[4][16][4];

    const int tid = threadIdx.x;
    const int bid = blockIdx.x;
    const int tx = tid & 15, ty = tid >> 4;   // ty 0..15
    const bool isL = (bid < 128);

    int h, b, m0, n0, dt;
    if (isL) {
        const int nt = bid & 1, mt = (bid >> 1) & 15;
        h = (bid >> 5) & 3; b = 0; dt = 0;
        m0 = mt * 64; n0 = nt * 64;
        {
            const int m_l = tid & 63, kq = tid >> 6;
            #pragma unroll
            for (int c = 0; c < 8; ++c) {
                const float4 v = *(const float4*)&x[(m0 + m_l) * Dc + kq * 32 + c * 4];
                As2[(kq * 16 + c * 2 + 0) * 64 + m_l] = packh(v.x, v.y);
                As2[(kq * 16 + c * 2 + 1) * 64 + m_l] = packh(v.z, v.w);
            }
        }
        {
            const int n_l = tid & 63, kq = tid >> 6;
            const float* Wb = W + (h * 2) * Dc * Dc;
            #pragma unroll
            for (int kk = 0; kk < 16; ++kk) {
                const int k2 = kq * 16 + kk;
                Bs2[k2 * 64 + n_l] =
                    packh(Wb[(2 * k2) * Dc + n0 + n_l], Wb[(2 * k2 + 1) * Dc + n0 + n_l]);
            }
        }
    } else {
        const int r_ = bid - 128;
        const int jt = r_ & 3;
        dt = (r_ >> 2) & 1;
        b  = (r_ >> 3) & 3;
        h  = (r_ >> 5) & 3;
        m0 = dt * 64;          // m-role = d
        n0 = jt * 64;          // n-role = j
        {
            const int d_l = tid & 63, kq = tid >> 6;
            const float* Wb = W + ((h * 2 + 1) * Dc) * Dc;
            #pragma unroll
            for (int kk = 0; kk < 16; ++kk) {
                const int k2 = kq * 16 + kk;
                As2[k2 * 64 + d_l] =
                    packh(Wb[(2 * k2) * Dc + m0 + d_l], Wb[(2 * k2 + 1) * Dc + m0 + d_l]);
            }
        }
        {
            const int j_l = tid & 63, kq = tid >> 6;
            #pragma unroll
            for (int c = 0; c < 8; ++c) {
                const float4 v = *(const float4*)&x[(b * Kc + n0 + j_l) * Dc + kq * 32 + c * 4];
                Bs2[(kq * 16 + c * 2 + 0) * 64 + j_l] = packh(v.x, v.y);
                Bs2[(kq * 16 + c * 2 + 1) * 64 + j_l] = packh(v.z, v.w);
            }
        }
    }
    __syncthreads();

    float acc[4][4];
    #pragma unroll
    for (int r = 0; r < 4; ++r)
        #pragma unroll
        for (int c = 0; c < 4; ++c) acc[r][c] = 0.f;

    #pragma unroll 8
    for (int k2 = 0; k2 < 64; ++k2) {
        const uint4 xa = *(const uint4*)&As2[k2 * 64 + ty * 4];   // 4 m x k-pair
        const uint4 wb = *(const uint4*)&Bs2[k2 * 64 + tx * 4];   // 4 n x k-pair
        acc[0][0] = dot2h(xa.x, wb.x, acc[0][0]);
        acc[0][1] = dot2h(xa.x, wb.y, acc[0][1]);
        acc[0][2] = dot2h(xa.x, wb.z, acc[0][2]);
        acc[0][3] = dot2h(xa.x, wb.w, acc[0][3]);
        acc[1][0] = dot2h(xa.y, wb.x, acc[1][0]);
        acc[1][1] = dot2h(xa.y, wb.y, acc[1][1]);
        acc[1][2] = dot2h(xa.y, wb.z, acc[1][2]);
        acc[1][3] = dot2h(xa.y, wb.w, acc[1][3]);
        acc[2][0] = dot2h(xa.z, wb.x, acc[2][0]);
        acc[2][1] = dot2h(xa.z, wb.y, acc[2][1]);
        acc[2][2] = dot2h(xa.z, wb.z, acc[2][2]);
        acc[2][3] = dot2h(xa.z, wb.w, acc[2][3]);
        acc[3][0] = dot2h(xa.w, wb.x, acc[3][0]);
        acc[3][1] = dot2h(xa.w, wb.y, acc[3][1]);
        acc[3][2] = dot2h(xa.w, wb.z, acc[3][2]);
        acc[3][3] = dot2h(xa.w, wb.w, acc[3][3]);
    }

    if (isL) {
        const float4 lv = *(const float4*)&lin_b[h * Dc + n0 + tx * 4];
        #pragma unroll
        for (int r = 0; r < 4; ++r) {
            uint2 pk;
            pk.x = packh(acc[r][0] + lv.x, acc[r][1] + lv.y);
            pk.y = packh(acc[r][2] + lv.z, acc[r][3] + lv.w);
            *(uint2*)&Lpp[(h * Mc + m0 + ty * 4 + r) * 64 + (n0 >> 1) + tx * 2] = pk;
        }
    } else {
        #pragma unroll
        for (int rp = 0; rp < 2; ++rp) {
            uint4 pk;
            pk.x = packh(acc[2 * rp][0], acc[2 * rp + 1][0]);
            pk.y = packh(acc[2 * rp][1], acc[2 * rp + 1][1]);
            pk.z = packh(acc[2 * rp][2], acc[2 * rp + 1][2]);
            pk.w = packh(acc[2 * rp][3], acc[2 * rp + 1][3]);
            *(uint4*)&Rtp[((h * 4 + b) * 64 + (m0 >> 1) + ty * 2 + rp) * Kc + n0 + tx * 4] = pk;
        }
        const float4 av = *(const float4*)&a[h * Dc + m0 + ty * 4];
        float p0 = 0.4f * (av.x * acc[0][0] + av.y * acc[1][0] + av.z * acc[2][0] + av.w * acc[3][0]);
        float p1 = 0.4f * (av.x * acc[0][1] + av.y * acc[1][1] + av.z * acc[2][1] + av.w * acc[3][1]);
        float p2 = 0.4f * (av.x * acc[0][2] + av.y * acc[1][2] + av.z * acc[2][2] + av.w * acc[3][2]);
        float p3 = 0.4f * (av.x * acc[0][3] + av.y * acc[1][3] + av.z * acc[2][3] + av.w * acc[3][3]);
        p0 += __shfl_xor(p0, 16, 64); p0 += __shfl_xor(p0, 32, 64);
        p1 += __shfl_xor(p1, 16, 64); p1 += __shfl_xor(p1, 32, 64);
        p2 += __shfl_xor(p2, 16, 64); p2 += __shfl_xor(p2, 32, 64);
        p3 += __shfl_xor(p3, 16, 64); p3 += __shfl_xor(p3, 32, 64);
        if (((tid >> 4) & 3) == 0) {
            const int w = tid >> 6;
            red[w][tx][0] = p0; red[w][tx][1] = p1;
            red[w][tx][2] = p2; red[w][tx][3] = p3;
        }
        __syncthreads();
        if (tid < 64) {
            const int txl = tid >> 2, c = tid & 3;
            const float v = red[0][txl][c] + red[1][txl][c] + red[2][txl][c] + red[3][txl][c];
            eb[((h * 4 + b) * 2 + dt) * Kc + n0 + tid] = 1.5f * v;
        }
    }
}

// ---------------------------------------------------------------------------
// K2 (512 blocks = (b, 128 i-tiles of 2 rows), 256 thr, 2 blk/CU, b pinned
// per XCD): wave w = head w; thread (w, j4) owns e[2i][4j] over the FULL
// d=128 (64 packed pairs). eb/bias hoisted above the e-loop; wave-local
// shuffle softmax; P-bar in LDS; single PV (unroll 8) -> out.
// ---------------------------------------------------------------------------
#define E4(ACC, LPV)                               \
    ACC.x = estep(rr.x, LPV, av, ACC.x);           \
    ACC.y = estep(rr.y, LPV, av, ACC.y);           \
    ACC.z = estep(rr.z, LPV, av, ACC.z);           \
    ACC.w = estep(rr.w, LPV, av, ACC.w);

__global__ __launch_bounds__(256) void k2(const float* __restrict__ x,
                                          const float* __restrict__ a,
                                          const float* __restrict__ bias,
                                          const unsigned int* __restrict__ Lpp,
                                          const unsigned int* __restrict__ Rtp,
                                          const float* __restrict__ eb,
                                          float* __restrict__ out) {
    __shared__ float red[256 * 12];           // 12 KB: per-head P (4x2x256), then PV scratch
    __shared__ unsigned int lpT2[4 * 64 * 2]; // [h][dp][i] 2 KB packed-f16 Lp
    __shared__ unsigned int aa2s[4 * 64];     // [h][dp] packed-f16 0.4*a pairs 1 KB
    __shared__ float plbar[2 * Kc];           // fp32 P-bar 2 KB

    const int tid = threadIdx.x;
    const int L = blockIdx.x;
    // XCD-pin: L&7 -> XCD; b = xcd>>1 (2 XCDs per b); it from remaining bits.
    const int xcd = L & 7;
    const int b = xcd >> 1;
    const int it = ((L >> 3) << 1) | (xcd & 1);   // 0..127
    const int i0 = it * 2;

    {   // stage lpT2[h][dp][i]: thread -> (h = tid>>6, dp = tid&63), both i rows
        const int hs = tid >> 6, dp = tid & 63;
        uint2 v;
        v.x = Lpp[(hs * Mc + b * Kc + i0 + 0) * 64 + dp];
        v.y = Lpp[(hs * Mc + b * Kc + i0 + 1) * 64 + dp];
        *(uint2*)&lpT2[(hs * 64 + dp) * 2] = v;
        aa2s[tid] = packh(0.4f * a[hs * Dc + 2 * dp], 0.4f * a[hs * Dc + 2 * dp + 1]);
    }
    __syncthreads();

    const int h = tid >> 6, j4 = tid & 63;    // wave = head
    const int hb = h * 4 + b;

    // hoisted epilogue loads: latency hides under the e-loop
    const float4 ebv0 = *(const float4*)&eb[(hb * 2 + 0) * Kc + j4 * 4];
    const float4 ebv1 = *(const float4*)&eb[(hb * 2 + 1) * Kc + j4 * 4];
    const float4 bv0  = *(const float4*)&bias[(h * Kc + i0 + 0) * Kc + j4 * 4];
    const float4 bv1  = *(const float4*)&bias[(h * Kc + i0 + 1) * Kc + j4 * 4];

    // ---- e-phase: full d in-thread, acc[2 rows][4 j] ----
    float4 acc0 = make_float4(0.f, 0.f, 0.f, 0.f);
    float4 acc1 = make_float4(0.f, 0.f, 0.f, 0.f);
    {
        const unsigned int* rb = Rtp + (hb * 64) * Kc + j4 * 4;
        const unsigned int* lt = lpT2 + (h * 64) * 2;
        const unsigned int* at = aa2s + h * 64;
        #pragma unroll 8
        for (int dp = 0; dp < 64; ++dp) {
            const uint4 rr = *(const uint4*)(rb + dp * Kc);    // 4 j x 2 d (global, L2-hot, 1KB/wave)
            const uint2 lp2 = *(const uint2*)(lt + dp * 2);    // 2 i x 2 d (LDS b64 broadcast)
            const h2_t av = u2h(at[dp]);                       // LDS b32 broadcast
            E4(acc0, lp2.x);
            E4(acc1, lp2.y);
        }
    }

    // ---- epilogue + softmax (wave-local, 2 rows) ----
    {
        const float jx = ebv0.x + ebv1.x, jy = ebv0.y + ebv1.y;
        const float jz = ebv0.z + ebv1.z, jw = ebv0.w + ebv1.w;
        acc0.x += jx + bv0.x; acc0.y += jy + bv0.y;
        acc0.z += jz + bv0.z; acc0.w += jw + bv0.w;
        acc1.x += jx + bv1.x; acc1.y += jy + bv1.y;
        acc1.z += jz + bv1.z; acc1.w += jw + bv1.w;

        {
            float m = fmaxf(fmaxf(acc0.x, acc0.y), fmaxf(acc0.z, acc0.w));
            #pragma unroll
            for (int off = 1; off < 64; off <<= 1) m = fmaxf(m, __shfl_xor(m, off, 64));
            const float p0 = __expf(acc0.x - m), p1 = __expf(acc0.y - m);
            const float p2 = __expf(acc0.z - m), p3 = __expf(acc0.w - m);
            float s = p0 + p1 + p2 + p3;
            #pragma unroll
            for (int off = 1; off < 64; off <<= 1) s += __shfl_xor(s, off, 64);
            const float sc = 0.25f / s;     // fold mean over H
            *(float4*)&red[h * 512 + 0 * Kc + j4 * 4] =
                make_float4(p0 * sc, p1 * sc, p2 * sc, p3 * sc);
        }
        {
            float m = fmaxf(fmaxf(acc1.x, acc1.y), fmaxf(acc1.z, acc1.w));
            #pragma unroll
            for (int off = 1; off < 64; off <<= 1) m = fmaxf(m, __shfl_xor(m, off, 64));
            const float p0 = __expf(acc1.x - m), p1 = __expf(acc1.y - m);
            const float p2 = __expf(acc1.z - m), p3 = __expf(acc1.w - m);
            float s = p0 + p1 + p2 + p3;
            #pragma unroll
            for (int off = 1; off < 64; off <<= 1) s += __shfl_xor(s, off, 64);
            const float sc = 0.25f / s;
            *(float4*)&red[h * 512 + 1 * Kc + j4 * 4] =
                make_float4(p0 * sc, p1 * sc, p2 * sc, p3 * sc);
        }
    }
    __syncthreads();

    // ---- P-bar = sum over 4 heads ----
    if (tid < 128) {
        const int r = tid >> 6, c = tid & 63;
        float4 s = make_float4(0.f, 0.f, 0.f, 0.f);
        #pragma unroll
        for (int w4 = 0; w4 < 4; ++w4) {
            const float4 v = *(const float4*)&red[w4 * 512 + r * Kc + c * 4];
            s.x += v.x; s.y += v.y; s.z += v.z; s.w += v.w;
        }
        *(float4*)&plbar[r * Kc + c * 4] = s;
    }
    __syncthreads();

    // ---- single PV with P-bar: out[i][d] = sum_j plbar[i][j] * x[b][j][d] ----
    const int jq = tid >> 5, dd4 = tid & 31;
    float4 o0 = make_float4(0.f, 0.f, 0.f, 0.f);
    float4 o1 = make_float4(0.f, 0.f, 0.f, 0.f);
    {
        const float* xb = x + (b * Kc) * Dc + dd4 * 4;
        #pragma unroll 8
        for (int jj = 0; jj < 32; ++jj) {
            const int j = jj * 8 + jq;
            const float4 xv = *(const float4*)(xb + j * Dc);   // global, L2-hot
            const float pv0 = plbar[j];                         // LDS broadcast
            const float pv1 = plbar[Kc + j];
            o0.x = fmaf(pv0, xv.x, o0.x); o0.y = fmaf(pv0, xv.y, o0.y);
            o0.z = fmaf(pv0, xv.z, o0.z); o0.w = fmaf(pv0, xv.w, o0.w);
            o1.x = fmaf(pv1, xv.x, o1.x); o1.y = fmaf(pv1, xv.y, o1.y);
            o1.z = fmaf(pv1, xv.z, o1.z); o1.w = fmaf(pv1, xv.w, o1.w);
        }
    }
    {
        float* myred = red + (jq * 32 + dd4) * 12;
        *(float4*)&myred[0] = o0;
        *(float4*)&myred[4] = o1;
    }
    __syncthreads();
    if (tid < 64) {
        const int i_f = tid >> 5, dd_f = tid & 31;
        float4 s = make_float4(0.f, 0.f, 0.f, 0.f);
        #pragma unroll
        for (int q = 0; q < 8; ++q) {
            const float4 v = *(const float4*)&red[(q * 32 + dd_f) * 12 + i_f * 4];
            s.x += v.x; s.y += v.y; s.z += v.z; s.w += v.w;
        }
        *(float4*)&out[(b * Kc + i0 + i_f) * Dc + dd_f * 4] = s;
    }
}

extern "C" void kernel_launch(void* const* d_in, const int* in_sizes, int n_in,
                              void* d_out, int out_size, void* d_ws, size_t ws_size,
                              hipStream_t stream) {
    const float* x     = (const float*)d_in[0];
    const float* W     = (const float*)d_in[1];
    const float* lin_b = (const float*)d_in[2];
    const float* a     = (const float*)d_in[3];
    const float* bias  = (const float*)d_in[4];
    float* out = (float*)d_out;

    unsigned int*   Lpp = (unsigned int*)d_ws;                // f16x2 [H][M][64]   (1 MB)
    unsigned int*   Rtp = Lpp + 4 * Mc * 64;                  // f16x2 [16][64][K]  (1 MB)
    float*          eb  = (float*)(Rtp + 16 * 64 * Kc);       // fp32  [16*2][K]    (32 KB)

    k1<<<256, 256, 0, stream>>>(x, W, lin_b, a, Lpp, Rtp, eb);
    k2<<<512, 256, 0, stream>>>(x, a, bias, Lpp, Rtp, eb, out);
}

// Round 16
// 23.191 us; speedup vs baseline: 1.0902x; 1.0130x over previous
//
#include <hip/hip_runtime.h>
#include <math.h>

// B=4, K=256, D=128, H=4, alpha=0.2
// leaky(s) = 0.6*s + 0.4*|s|  (exact for alpha=0.2)
// e_ij = [0.6*(a.Lp_i) cancels in softmax] + 0.6*(a.R_j) + sum_d (0.4 a_d)|Lp_id + R_jd| + bias_ij
// mean_h(P_h @ x) = (mean_h P_h) @ x.
// k1: f16-pair dot2 GEMM (512 thr, 2 waves/SIMD) -> Lpp/Rtp packed f16 + eb.
// k2 (champion): wave = head, thread owns full d=128 for (2i x 4j); P-bar LDS; single PV.
constexpr int Kc = 256, Dc = 128, Mc = 1024;    // Mc = B*K

typedef _Float16 h2_t __attribute__((ext_vector_type(2)));
union U32H2 { unsigned int u; h2_t h; };
__device__ inline h2_t u2h(unsigned int u) { U32H2 x; x.u = u; return x.h; }
__device__ inline unsigned int h2u(h2_t h) { U32H2 x; x.h = h; return x.u; }
__device__ inline unsigned int packh(float a, float b) {
    h2_t h; h.x = (_Float16)a; h.y = (_Float16)b; return h2u(h);
}

#if __has_builtin(__builtin_amdgcn_fdot2)
__device__ inline float dot2h(unsigned int a, unsigned int b, float c) {
    return __builtin_amdgcn_fdot2(u2h(a), u2h(b), c, false);
}
#else
__device__ inline float dot2h(unsigned int a, unsigned int b, float c) {
    h2_t ah = u2h(a), bh = u2h(b);
    return fmaf((float)ah.x, (float)bh.x, fmaf((float)ah.y, (float)bh.y, c));
}
#endif

// acc += (0.4a_2d)|l_2d + r_2d| + (0.4a_2d+1)|l_2d+1 + r_2d+1|, f32 accumulate
__device__ inline float estep(unsigned int r, unsigned int l, h2_t av, float acc) {
    h2_t s = u2h(r) + u2h(l);                       // v_pk_add_f16
    unsigned int t = h2u(s) & 0x7FFF7FFFu;          // packed abs
#if __has_builtin(__builtin_amdgcn_fdot2)
    return __builtin_amdgcn_fdot2(u2h(t), av, acc, false);   // v_dot2_f32_f16
#else
    h2_t th = u2h(t);
    return fmaf((float)th.x, (float)av.x, fmaf((float)th.y, (float)av.y, acc));
#endif
}

// ---------------------------------------------------------------------------
// K1 (256 blocks, 512 thr = 8 waves = 2 waves/SIMD): 64x64-tile GEMM,
// 2x4 acc/thread, f16-pair dot2 inner loop.
//   bid <  128 : Lpp[h][m][dp] = packed-f16 pair of (x@W_src + lin_b)
//   bid >= 128 : Rtp[hb][dp][j] = packed-f16 pair of (x@W_dst)^T
//                + eb[(hb*2+dt)][j] = 1.5 * sum_{d in 64-slice} 0.4*a_d*R_jd (fp32)
// ---------------------------------------------------------------------------
__global__ __launch_bounds__(512) void k1(const float* __restrict__ x,
                                          const float* __restrict__ W,
                                          const float* __restrict__ lin_b,
                                          const float* __restrict__ a,
                                          unsigned int* __restrict__ Lpp,
                                          unsigned int* __restrict__ Rtp,
                                          float* __restrict__ eb) {
    __shared__ unsigned int As2[64 * 64];   // [k2][m-role] packed k-pairs, 16 KB
    __shared__ unsigned int Bs2[64 * 64];   // [k2][n-role] packed k-pairs, 16 KB
    __shared__ float red[8][16][4];

    const int tid = threadIdx.x;
    const int bid = blockIdx.x;
    const int tx = tid & 15, ty = tid >> 4;   // ty 0..31
    const bool isL = (bid < 128);

    int h, b, m0, n0, dt;
    if (isL) {
        const int nt = bid & 1, mt = (bid >> 1) & 15;
        h = (bid >> 5) & 3; b = 0; dt = 0;
        m0 = mt * 64; n0 = nt * 64;
        // As2 = x rows m0.., packed along k (8 kq-groups of 16 k)
        {
            const int m_l = tid & 63, kq = tid >> 6;   // kq 0..7
            #pragma unroll
            for (int c = 0; c < 4; ++c) {
                const float4 v = *(const float4*)&x[(m0 + m_l) * Dc + kq * 16 + c * 4];
                As2[(kq * 8 + c * 2 + 0) * 64 + m_l] = packh(v.x, v.y);
                As2[(kq * 8 + c * 2 + 1) * 64 + m_l] = packh(v.z, v.w);
            }
        }
        // Bs2 = W_src, packed along k (rows)
        {
            const int n_l = tid & 63, kq = tid >> 6;
            const float* Wb = W + (h * 2) * Dc * Dc;
            #pragma unroll
            for (int kk = 0; kk < 8; ++kk) {
                const int k2 = kq * 8 + kk;
                Bs2[k2 * 64 + n_l] =
                    packh(Wb[(2 * k2) * Dc + n0 + n_l], Wb[(2 * k2 + 1) * Dc + n0 + n_l]);
            }
        }
    } else {
        const int r_ = bid - 128;
        const int jt = r_ & 3;
        dt = (r_ >> 2) & 1;
        b  = (r_ >> 3) & 3;
        h  = (r_ >> 5) & 3;
        m0 = dt * 64;          // m-role = d
        n0 = jt * 64;          // n-role = j
        // As2 = W_dst cols d0.., packed along k (rows)
        {
            const int d_l = tid & 63, kq = tid >> 6;
            const float* Wb = W + ((h * 2 + 1) * Dc) * Dc;
            #pragma unroll
            for (int kk = 0; kk < 8; ++kk) {
                const int k2 = kq * 8 + kk;
                As2[k2 * 64 + d_l] =
                    packh(Wb[(2 * k2) * Dc + m0 + d_l], Wb[(2 * k2 + 1) * Dc + m0 + d_l]);
            }
        }
        // Bs2 = x rows b*K + j0.., packed along k
        {
            const int j_l = tid & 63, kq = tid >> 6;
            #pragma unroll
            for (int c = 0; c < 4; ++c) {
                const float4 v = *(const float4*)&x[(b * Kc + n0 + j_l) * Dc + kq * 16 + c * 4];
                Bs2[(kq * 8 + c * 2 + 0) * 64 + j_l] = packh(v.x, v.y);
                Bs2[(kq * 8 + c * 2 + 1) * 64 + j_l] = packh(v.z, v.w);
            }
        }
    }
    __syncthreads();

    float acc[2][4];
    #pragma unroll
    for (int r = 0; r < 2; ++r)
        #pragma unroll
        for (int c = 0; c < 4; ++c) acc[r][c] = 0.f;

    #pragma unroll 8
    for (int k2 = 0; k2 < 64; ++k2) {
        const uint2 xa = *(const uint2*)&As2[k2 * 64 + ty * 2];   // 2 m x k-pair
        const uint4 wb = *(const uint4*)&Bs2[k2 * 64 + tx * 4];   // 4 n x k-pair
        acc[0][0] = dot2h(xa.x, wb.x, acc[0][0]);
        acc[0][1] = dot2h(xa.x, wb.y, acc[0][1]);
        acc[0][2] = dot2h(xa.x, wb.z, acc[0][2]);
        acc[0][3] = dot2h(xa.x, wb.w, acc[0][3]);
        acc[1][0] = dot2h(xa.y, wb.x, acc[1][0]);
        acc[1][1] = dot2h(xa.y, wb.y, acc[1][1]);
        acc[1][2] = dot2h(xa.y, wb.z, acc[1][2]);
        acc[1][3] = dot2h(xa.y, wb.w, acc[1][3]);
    }

    if (isL) {
        const float4 lv = *(const float4*)&lin_b[h * Dc + n0 + tx * 4];
        #pragma unroll
        for (int r = 0; r < 2; ++r) {
            uint2 pk;
            pk.x = packh(acc[r][0] + lv.x, acc[r][1] + lv.y);
            pk.y = packh(acc[r][2] + lv.z, acc[r][3] + lv.w);
            *(uint2*)&Lpp[(h * Mc + m0 + ty * 2 + r) * 64 + (n0 >> 1) + tx * 2] = pk;
        }
    } else {
        // Rtp pack along d (m-role): thread owns d-pair dp = (m0>>1) + ty
        {
            uint4 pk;
            pk.x = packh(acc[0][0], acc[1][0]);
            pk.y = packh(acc[0][1], acc[1][1]);
            pk.z = packh(acc[0][2], acc[1][2]);
            pk.w = packh(acc[0][3], acc[1][3]);
            *(uint4*)&Rtp[((h * 4 + b) * 64 + (m0 >> 1) + ty) * Kc + n0 + tx * 4] = pk;
        }
        // eb partial: p_c = 0.4 * sum_r a[m0+ty*2+r] * acc[r][c]
        const float2 av = *(const float2*)&a[h * Dc + m0 + ty * 2];
        float p0 = 0.4f * (av.x * acc[0][0] + av.y * acc[1][0]);
        float p1 = 0.4f * (av.x * acc[0][1] + av.y * acc[1][1]);
        float p2 = 0.4f * (av.x * acc[0][2] + av.y * acc[1][2]);
        float p3 = 0.4f * (av.x * acc[0][3] + av.y * acc[1][3]);
        // reduce over the 4 ty values within each wave (tid bits 4..5)
        p0 += __shfl_xor(p0, 16, 64); p0 += __shfl_xor(p0, 32, 64);
        p1 += __shfl_xor(p1, 16, 64); p1 += __shfl_xor(p1, 32, 64);
        p2 += __shfl_xor(p2, 16, 64); p2 += __shfl_xor(p2, 32, 64);
        p3 += __shfl_xor(p3, 16, 64); p3 += __shfl_xor(p3, 32, 64);
        if (((tid >> 4) & 3) == 0) {
            const int w = tid >> 6;
            red[w][tx][0] = p0; red[w][tx][1] = p1;
            red[w][tx][2] = p2; red[w][tx][3] = p3;
        }
        __syncthreads();
        if (tid < 64) {
            const int txl = tid >> 2, c = tid & 3;
            float v = 0.f;
            #pragma unroll
            for (int w8 = 0; w8 < 8; ++w8) v += red[w8][txl][c];
            eb[((h * 4 + b) * 2 + dt) * Kc + n0 + tid] = 1.5f * v;
        }
    }
}

// ---------------------------------------------------------------------------
// K2 (512 blocks = (b, 128 i-tiles of 2 rows), 256 thr, 2 blk/CU, b pinned
// per XCD): wave w = head w; thread (w, j4) owns e[2i][4j] over the FULL
// d=128 (64 packed pairs). eb/bias hoisted above the e-loop; wave-local
// shuffle softmax; P-bar in LDS; single PV (unroll 8) -> out.
// (byte-identical to R15 champion)
// ---------------------------------------------------------------------------
#define E4(ACC, LPV)                               \
    ACC.x = estep(rr.x, LPV, av, ACC.x);           \
    ACC.y = estep(rr.y, LPV, av, ACC.y);           \
    ACC.z = estep(rr.z, LPV, av, ACC.z);           \
    ACC.w = estep(rr.w, LPV, av, ACC.w);

__global__ __launch_bounds__(256) void k2(const float* __restrict__ x,
                                          const float* __restrict__ a,
                                          const float* __restrict__ bias,
                                          const unsigned int* __restrict__ Lpp,
                                          const unsigned int* __restrict__ Rtp,
                                          const float* __restrict__ eb,
                                          float* __restrict__ out) {
    __shared__ float red[256 * 12];           // 12 KB: per-head P (4x2x256), then PV scratch
    __shared__ unsigned int lpT2[4 * 64 * 2]; // [h][dp][i] 2 KB packed-f16 Lp
    __shared__ unsigned int aa2s[4 * 64];     // [h][dp] packed-f16 0.4*a pairs 1 KB
    __shared__ float plbar[2 * Kc];           // fp32 P-bar 2 KB

    const int tid = threadIdx.x;
    const int L = blockIdx.x;
    // XCD-pin: L&7 -> XCD; b = xcd>>1 (2 XCDs per b); it from remaining bits.
    const int xcd = L & 7;
    const int b = xcd >> 1;
    const int it = ((L >> 3) << 1) | (xcd & 1);   // 0..127
    const int i0 = it * 2;

    {   // stage lpT2[h][dp][i]: thread -> (h = tid>>6, dp = tid&63), both i rows
        const int hs = tid >> 6, dp = tid & 63;
        uint2 v;
        v.x = Lpp[(hs * Mc + b * Kc + i0 + 0) * 64 + dp];
        v.y = Lpp[(hs * Mc + b * Kc + i0 + 1) * 64 + dp];
        *(uint2*)&lpT2[(hs * 64 + dp) * 2] = v;
        aa2s[tid] = packh(0.4f * a[hs * Dc + 2 * dp], 0.4f * a[hs * Dc + 2 * dp + 1]);
    }
    __syncthreads();

    const int h = tid >> 6, j4 = tid & 63;    // wave = head
    const int hb = h * 4 + b;

    // hoisted epilogue loads: latency hides under the e-loop
    const float4 ebv0 = *(const float4*)&eb[(hb * 2 + 0) * Kc + j4 * 4];
    const float4 ebv1 = *(const float4*)&eb[(hb * 2 + 1) * Kc + j4 * 4];
    const float4 bv0  = *(const float4*)&bias[(h * Kc + i0 + 0) * Kc + j4 * 4];
    const float4 bv1  = *(const float4*)&bias[(h * Kc + i0 + 1) * Kc + j4 * 4];

    // ---- e-phase: full d in-thread, acc[2 rows][4 j] ----
    float4 acc0 = make_float4(0.f, 0.f, 0.f, 0.f);
    float4 acc1 = make_float4(0.f, 0.f, 0.f, 0.f);
    {
        const unsigned int* rb = Rtp + (hb * 64) * Kc + j4 * 4;
        const unsigned int* lt = lpT2 + (h * 64) * 2;
        const unsigned int* at = aa2s + h * 64;
        #pragma unroll 8
        for (int dp = 0; dp < 64; ++dp) {
            const uint4 rr = *(const uint4*)(rb + dp * Kc);    // 4 j x 2 d (global, L2-hot, 1KB/wave)
            const uint2 lp2 = *(const uint2*)(lt + dp * 2);    // 2 i x 2 d (LDS b64 broadcast)
            const h2_t av = u2h(at[dp]);                       // LDS b32 broadcast
            E4(acc0, lp2.x);
            E4(acc1, lp2.y);
        }
    }

    // ---- epilogue + softmax (wave-local, 2 rows) ----
    {
        const float jx = ebv0.x + ebv1.x, jy = ebv0.y + ebv1.y;
        const float jz = ebv0.z + ebv1.z, jw = ebv0.w + ebv1.w;
        acc0.x += jx + bv0.x; acc0.y += jy + bv0.y;
        acc0.z += jz + bv0.z; acc0.w += jw + bv0.w;
        acc1.x += jx + bv1.x; acc1.y += jy + bv1.y;
        acc1.z += jz + bv1.z; acc1.w += jw + bv1.w;

        {
            float m = fmaxf(fmaxf(acc0.x, acc0.y), fmaxf(acc0.z, acc0.w));
            #pragma unroll
            for (int off = 1; off < 64; off <<= 1) m = fmaxf(m, __shfl_xor(m, off, 64));
            const float p0 = __expf(acc0.x - m), p1 = __expf(acc0.y - m);
            const float p2 = __expf(acc0.z - m), p3 = __expf(acc0.w - m);
            float s = p0 + p1 + p2 + p3;
            #pragma unroll
            for (int off = 1; off < 64; off <<= 1) s += __shfl_xor(s, off, 64);
            const float sc = 0.25f / s;     // fold mean over H
            *(float4*)&red[h * 512 + 0 * Kc + j4 * 4] =
                make_float4(p0 * sc, p1 * sc, p2 * sc, p3 * sc);
        }
        {
            float m = fmaxf(fmaxf(acc1.x, acc1.y), fmaxf(acc1.z, acc1.w));
            #pragma unroll
            for (int off = 1; off < 64; off <<= 1) m = fmaxf(m, __shfl_xor(m, off, 64));
            const float p0 = __expf(acc1.x - m), p1 = __expf(acc1.y - m);
            const float p2 = __expf(acc1.z - m), p3 = __expf(acc1.w - m);
            float s = p0 + p1 + p2 + p3;
            #pragma unroll
            for (int off = 1; off < 64; off <<= 1) s += __shfl_xor(s, off, 64);
            const float sc = 0.25f / s;
            *(float4*)&red[h * 512 + 1 * Kc + j4 * 4] =
                make_float4(p0 * sc, p1 * sc, p2 * sc, p3 * sc);
        }
    }
    __syncthreads();

    // ---- P-bar = sum over 4 heads ----
    if (tid < 128) {
        const int r = tid >> 6, c = tid & 63;
        float4 s = make_float4(0.f, 0.f, 0.f, 0.f);
        #pragma unroll
        for (int w4 = 0; w4 < 4; ++w4) {
            const float4 v = *(const float4*)&red[w4 * 512 + r * Kc + c * 4];
            s.x += v.x; s.y += v.y; s.z += v.z; s.w += v.w;
        }
        *(float4*)&plbar[r * Kc + c * 4] = s;
    }
    __syncthreads();

    // ---- single PV with P-bar: out[i][d] = sum_j plbar[i][j] * x[b][j][d] ----
    const int jq = tid >> 5, dd4 = tid & 31;
    float4 o0 = make_float4(0.f, 0.f, 0.f, 0.f);
    float4 o1 = make_float4(0.f, 0.f, 0.f, 0.f);
    {
        const float* xb = x + (b * Kc) * Dc + dd4 * 4;
        #pragma unroll 8
        for (int jj = 0; jj < 32; ++jj) {
            const int j = jj * 8 + jq;
            const float4 xv = *(const float4*)(xb + j * Dc);   // global, L2-hot
            const float pv0 = plbar[j];                         // LDS broadcast
            const float pv1 = plbar[Kc + j];
            o0.x = fmaf(pv0, xv.x, o0.x); o0.y = fmaf(pv0, xv.y, o0.y);
            o0.z = fmaf(pv0, xv.z, o0.z); o0.w = fmaf(pv0, xv.w, o0.w);
            o1.x = fmaf(pv1, xv.x, o1.x); o1.y = fmaf(pv1, xv.y, o1.y);
            o1.z = fmaf(pv1, xv.z, o1.z); o1.w = fmaf(pv1, xv.w, o1.w);
        }
    }
    {
        float* myred = red + (jq * 32 + dd4) * 12;
        *(float4*)&myred[0] = o0;
        *(float4*)&myred[4] = o1;
    }
    __syncthreads();
    if (tid < 64) {
        const int i_f = tid >> 5, dd_f = tid & 31;
        float4 s = make_float4(0.f, 0.f, 0.f, 0.f);
        #pragma unroll
        for (int q = 0; q < 8; ++q) {
            const float4 v = *(const float4*)&red[(q * 32 + dd_f) * 12 + i_f * 4];
            s.x += v.x; s.y += v.y; s.z += v.z; s.w += v.w;
        }
        *(float4*)&out[(b * Kc + i0 + i_f) * Dc + dd_f * 4] = s;
    }
}

extern "C" void kernel_launch(void* const* d_in, const int* in_sizes, int n_in,
                              void* d_out, int out_size, void* d_ws, size_t ws_size,
                              hipStream_t stream) {
    const float* x     = (const float*)d_in[0];
    const float* W     = (const float*)d_in[1];
    const float* lin_b = (const float*)d_in[2];
    const float* a     = (const float*)d_in[3];
    const float* bias  = (const float*)d_in[4];
    float* out = (float*)d_out;

    unsigned int*   Lpp = (unsigned int*)d_ws;                // f16x2 [H][M][64]   (1 MB)
    unsigned int*   Rtp = Lpp + 4 * Mc * 64;                  // f16x2 [16][64][K]  (1 MB)
    float*          eb  = (float*)(Rtp + 16 * 64 * Kc);       // fp32  [16*2][K]    (32 KB)

    k1<<<256, 512, 0, stream>>>(x, W, lin_b, a, Lpp, Rtp, eb);
    k2<<<512, 256, 0, stream>>>(x, a, bias, Lpp, Rtp, eb, out);
}

// Round 17
// 22.875 us; speedup vs baseline: 1.1052x; 1.0138x over previous
//
#include <hip/hip_runtime.h>
#include <math.h>

// B=4, K=256, D=128, H=4, alpha=0.2
// leaky(s) = 0.6*s + 0.4*|s|  (exact for alpha=0.2)
// e_ij = [0.6*(a.Lp_i) cancels in softmax] + 0.6*(a.R_j) + sum_d (0.4 a_d)|Lp_id + R_jd| + bias_ij
// mean_h(P_h @ x) = (mean_h P_h) @ x.
// k1: f16-pair dot2 GEMM (512 thr, 2 waves/SIMD) -> Lpp/Rtp packed f16 + eb.
// k2: wave = head, thread owns full d=128 for (2i x 4j); EXPLICIT register
//     double-buffering (depth 8) of the Rt and x global-load streams.
constexpr int Kc = 256, Dc = 128, Mc = 1024;    // Mc = B*K

typedef _Float16 h2_t __attribute__((ext_vector_type(2)));
union U32H2 { unsigned int u; h2_t h; };
__device__ inline h2_t u2h(unsigned int u) { U32H2 x; x.u = u; return x.h; }
__device__ inline unsigned int h2u(h2_t h) { U32H2 x; x.h = h; return x.u; }
__device__ inline unsigned int packh(float a, float b) {
    h2_t h; h.x = (_Float16)a; h.y = (_Float16)b; return h2u(h);
}

#if __has_builtin(__builtin_amdgcn_fdot2)
__device__ inline float dot2h(unsigned int a, unsigned int b, float c) {
    return __builtin_amdgcn_fdot2(u2h(a), u2h(b), c, false);
}
#else
__device__ inline float dot2h(unsigned int a, unsigned int b, float c) {
    h2_t ah = u2h(a), bh = u2h(b);
    return fmaf((float)ah.x, (float)bh.x, fmaf((float)ah.y, (float)bh.y, c));
}
#endif

// acc += (0.4a_2d)|l_2d + r_2d| + (0.4a_2d+1)|l_2d+1 + r_2d+1|, f32 accumulate
__device__ inline float estep(unsigned int r, unsigned int l, h2_t av, float acc) {
    h2_t s = u2h(r) + u2h(l);                       // v_pk_add_f16
    unsigned int t = h2u(s) & 0x7FFF7FFFu;          // packed abs
#if __has_builtin(__builtin_amdgcn_fdot2)
    return __builtin_amdgcn_fdot2(u2h(t), av, acc, false);   // v_dot2_f32_f16
#else
    h2_t th = u2h(t);
    return fmaf((float)th.x, (float)av.x, fmaf((float)th.y, (float)av.y, acc));
#endif
}

// ---------------------------------------------------------------------------
// K1 (256 blocks, 512 thr = 8 waves = 2 waves/SIMD): 64x64-tile GEMM,
// 2x4 acc/thread, f16-pair dot2 inner loop.  (byte-identical to R16)
// ---------------------------------------------------------------------------
__global__ __launch_bounds__(512) void k1(const float* __restrict__ x,
                                          const float* __restrict__ W,
                                          const float* __restrict__ lin_b,
                                          const float* __restrict__ a,
                                          unsigned int* __restrict__ Lpp,
                                          unsigned int* __restrict__ Rtp,
                                          float* __restrict__ eb) {
    __shared__ unsigned int As2[64 * 64];   // [k2][m-role] packed k-pairs, 16 KB
    __shared__ unsigned int Bs2[64 * 64];   // [k2][n-role] packed k-pairs, 16 KB
    __shared__ float red[8][16][4];

    const int tid = threadIdx.x;
    const int bid = blockIdx.x;
    const int tx = tid & 15, ty = tid >> 4;   // ty 0..31
    const bool isL = (bid < 128);

    int h, b, m0, n0, dt;
    if (isL) {
        const int nt = bid & 1, mt = (bid >> 1) & 15;
        h = (bid >> 5) & 3; b = 0; dt = 0;
        m0 = mt * 64; n0 = nt * 64;
        {
            const int m_l = tid & 63, kq = tid >> 6;   // kq 0..7
            #pragma unroll
            for (int c = 0; c < 4; ++c) {
                const float4 v = *(const float4*)&x[(m0 + m_l) * Dc + kq * 16 + c * 4];
                As2[(kq * 8 + c * 2 + 0) * 64 + m_l] = packh(v.x, v.y);
                As2[(kq * 8 + c * 2 + 1) * 64 + m_l] = packh(v.z, v.w);
            }
        }
        {
            const int n_l = tid & 63, kq = tid >> 6;
            const float* Wb = W + (h * 2) * Dc * Dc;
            #pragma unroll
            for (int kk = 0; kk < 8; ++kk) {
                const int k2 = kq * 8 + kk;
                Bs2[k2 * 64 + n_l] =
                    packh(Wb[(2 * k2) * Dc + n0 + n_l], Wb[(2 * k2 + 1) * Dc + n0 + n_l]);
            }
        }
    } else {
        const int r_ = bid - 128;
        const int jt = r_ & 3;
        dt = (r_ >> 2) & 1;
        b  = (r_ >> 3) & 3;
        h  = (r_ >> 5) & 3;
        m0 = dt * 64;          // m-role = d
        n0 = jt * 64;          // n-role = j
        {
            const int d_l = tid & 63, kq = tid >> 6;
            const float* Wb = W + ((h * 2 + 1) * Dc) * Dc;
            #pragma unroll
            for (int kk = 0; kk < 8; ++kk) {
                const int k2 = kq * 8 + kk;
                As2[k2 * 64 + d_l] =
                    packh(Wb[(2 * k2) * Dc + m0 + d_l], Wb[(2 * k2 + 1) * Dc + m0 + d_l]);
            }
        }
        {
            const int j_l = tid & 63, kq = tid >> 6;
            #pragma unroll
            for (int c = 0; c < 4; ++c) {
                const float4 v = *(const float4*)&x[(b * Kc + n0 + j_l) * Dc + kq * 16 + c * 4];
                Bs2[(kq * 8 + c * 2 + 0) * 64 + j_l] = packh(v.x, v.y);
                Bs2[(kq * 8 + c * 2 + 1) * 64 + j_l] = packh(v.z, v.w);
            }
        }
    }
    __syncthreads();

    float acc[2][4];
    #pragma unroll
    for (int r = 0; r < 2; ++r)
        #pragma unroll
        for (int c = 0; c < 4; ++c) acc[r][c] = 0.f;

    #pragma unroll 8
    for (int k2 = 0; k2 < 64; ++k2) {
        const uint2 xa = *(const uint2*)&As2[k2 * 64 + ty * 2];   // 2 m x k-pair
        const uint4 wb = *(const uint4*)&Bs2[k2 * 64 + tx * 4];   // 4 n x k-pair
        acc[0][0] = dot2h(xa.x, wb.x, acc[0][0]);
        acc[0][1] = dot2h(xa.x, wb.y, acc[0][1]);
        acc[0][2] = dot2h(xa.x, wb.z, acc[0][2]);
        acc[0][3] = dot2h(xa.x, wb.w, acc[0][3]);
        acc[1][0] = dot2h(xa.y, wb.x, acc[1][0]);
        acc[1][1] = dot2h(xa.y, wb.y, acc[1][1]);
        acc[1][2] = dot2h(xa.y, wb.z, acc[1][2]);
        acc[1][3] = dot2h(xa.y, wb.w, acc[1][3]);
    }

    if (isL) {
        const float4 lv = *(const float4*)&lin_b[h * Dc + n0 + tx * 4];
        #pragma unroll
        for (int r = 0; r < 2; ++r) {
            uint2 pk;
            pk.x = packh(acc[r][0] + lv.x, acc[r][1] + lv.y);
            pk.y = packh(acc[r][2] + lv.z, acc[r][3] + lv.w);
            *(uint2*)&Lpp[(h * Mc + m0 + ty * 2 + r) * 64 + (n0 >> 1) + tx * 2] = pk;
        }
    } else {
        {
            uint4 pk;
            pk.x = packh(acc[0][0], acc[1][0]);
            pk.y = packh(acc[0][1], acc[1][1]);
            pk.z = packh(acc[0][2], acc[1][2]);
            pk.w = packh(acc[0][3], acc[1][3]);
            *(uint4*)&Rtp[((h * 4 + b) * 64 + (m0 >> 1) + ty) * Kc + n0 + tx * 4] = pk;
        }
        const float2 av = *(const float2*)&a[h * Dc + m0 + ty * 2];
        float p0 = 0.4f * (av.x * acc[0][0] + av.y * acc[1][0]);
        float p1 = 0.4f * (av.x * acc[0][1] + av.y * acc[1][1]);
        float p2 = 0.4f * (av.x * acc[0][2] + av.y * acc[1][2]);
        float p3 = 0.4f * (av.x * acc[0][3] + av.y * acc[1][3]);
        p0 += __shfl_xor(p0, 16, 64); p0 += __shfl_xor(p0, 32, 64);
        p1 += __shfl_xor(p1, 16, 64); p1 += __shfl_xor(p1, 32, 64);
        p2 += __shfl_xor(p2, 16, 64); p2 += __shfl_xor(p2, 32, 64);
        p3 += __shfl_xor(p3, 16, 64); p3 += __shfl_xor(p3, 32, 64);
        if (((tid >> 4) & 3) == 0) {
            const int w = tid >> 6;
            red[w][tx][0] = p0; red[w][tx][1] = p1;
            red[w][tx][2] = p2; red[w][tx][3] = p3;
        }
        __syncthreads();
        if (tid < 64) {
            const int txl = tid >> 2, c = tid & 3;
            float v = 0.f;
            #pragma unroll
            for (int w8 = 0; w8 < 8; ++w8) v += red[w8][txl][c];
            eb[((h * 4 + b) * 2 + dt) * Kc + n0 + tid] = 1.5f * v;
        }
    }
}

// ---------------------------------------------------------------------------
// K2 (512 blocks = (b, 128 i-tiles of 2 rows), 256 thr, 2 blk/CU, b pinned
// per XCD): wave w = head w; thread (w, j4) owns e[2i][4j] over the FULL
// d=128.  Explicit depth-8 register double-buffer on the Rt stream (e-loop)
// and the x stream (PV) so 8 loads are always in flight ahead of consumption.
// ---------------------------------------------------------------------------
#define E4(ACC, LPV)                               \
    ACC.x = estep(rr.x, LPV, av, ACC.x);           \
    ACC.y = estep(rr.y, LPV, av, ACC.y);           \
    ACC.z = estep(rr.z, LPV, av, ACC.z);           \
    ACC.w = estep(rr.w, LPV, av, ACC.w);

__global__ __launch_bounds__(256) void k2(const float* __restrict__ x,
                                          const float* __restrict__ a,
                                          const float* __restrict__ bias,
                                          const unsigned int* __restrict__ Lpp,
                                          const unsigned int* __restrict__ Rtp,
                                          const float* __restrict__ eb,
                                          float* __restrict__ out) {
    __shared__ float red[256 * 12];           // 12 KB: per-head P (4x2x256), then PV scratch
    __shared__ unsigned int lpT2[4 * 64 * 2]; // [h][dp][i] 2 KB packed-f16 Lp
    __shared__ unsigned int aa2s[4 * 64];     // [h][dp] packed-f16 0.4*a pairs 1 KB
    __shared__ float plbar[2 * Kc];           // fp32 P-bar 2 KB

    const int tid = threadIdx.x;
    const int L = blockIdx.x;
    // XCD-pin: L&7 -> XCD; b = xcd>>1 (2 XCDs per b); it from remaining bits.
    const int xcd = L & 7;
    const int b = xcd >> 1;
    const int it = ((L >> 3) << 1) | (xcd & 1);   // 0..127
    const int i0 = it * 2;

    {   // stage lpT2[h][dp][i]: thread -> (h = tid>>6, dp = tid&63), both i rows
        const int hs = tid >> 6, dp = tid & 63;
        uint2 v;
        v.x = Lpp[(hs * Mc + b * Kc + i0 + 0) * 64 + dp];
        v.y = Lpp[(hs * Mc + b * Kc + i0 + 1) * 64 + dp];
        *(uint2*)&lpT2[(hs * 64 + dp) * 2] = v;
        aa2s[tid] = packh(0.4f * a[hs * Dc + 2 * dp], 0.4f * a[hs * Dc + 2 * dp + 1]);
    }
    __syncthreads();

    const int h = tid >> 6, j4 = tid & 63;    // wave = head
    const int hb = h * 4 + b;

    // hoisted epilogue loads: latency hides under the e-loop
    const float4 ebv0 = *(const float4*)&eb[(hb * 2 + 0) * Kc + j4 * 4];
    const float4 ebv1 = *(const float4*)&eb[(hb * 2 + 1) * Kc + j4 * 4];
    const float4 bv0  = *(const float4*)&bias[(h * Kc + i0 + 0) * Kc + j4 * 4];
    const float4 bv1  = *(const float4*)&bias[(h * Kc + i0 + 1) * Kc + j4 * 4];

    // ---- e-phase: full d in-thread, acc[2 rows][4 j], depth-8 load pipeline ----
    float4 acc0 = make_float4(0.f, 0.f, 0.f, 0.f);
    float4 acc1 = make_float4(0.f, 0.f, 0.f, 0.f);
    {
        const unsigned int* rb = Rtp + (hb * 64) * Kc + j4 * 4;
        const unsigned int* lt = lpT2 + (h * 64) * 2;
        const unsigned int* at = aa2s + h * 64;

        uint4 cur[8], nxt[8];
        #pragma unroll
        for (int i = 0; i < 8; ++i) cur[i] = *(const uint4*)(rb + i * Kc);

        #pragma unroll
        for (int bb = 0; bb < 8; ++bb) {
            // issue ALL next-batch loads before consuming the current batch
            #pragma unroll
            for (int i = 0; i < 8; ++i)
                if (bb < 7) nxt[i] = *(const uint4*)(rb + ((bb + 1) * 8 + i) * Kc);
            #pragma unroll
            for (int i = 0; i < 8; ++i) {
                const int dp = bb * 8 + i;
                const uint4 rr = cur[i];
                const uint2 lp2 = *(const uint2*)(lt + dp * 2);   // LDS b64 broadcast
                const h2_t av = u2h(at[dp]);                      // LDS b32 broadcast
                E4(acc0, lp2.x);
                E4(acc1, lp2.y);
            }
            #pragma unroll
            for (int i = 0; i < 8; ++i)
                if (bb < 7) cur[i] = nxt[i];
        }
    }

    // ---- epilogue + softmax (wave-local, 2 rows) ----
    {
        const float jx = ebv0.x + ebv1.x, jy = ebv0.y + ebv1.y;
        const float jz = ebv0.z + ebv1.z, jw = ebv0.w + ebv1.w;
        acc0.x += jx + bv0.x; acc0.y += jy + bv0.y;
        acc0.z += jz + bv0.z; acc0.w += jw + bv0.w;
        acc1.x += jx + bv1.x; acc1.y += jy + bv1.y;
        acc1.z += jz + bv1.z; acc1.w += jw + bv1.w;

        {
            float m = fmaxf(fmaxf(acc0.x, acc0.y), fmaxf(acc0.z, acc0.w));
            #pragma unroll
            for (int off = 1; off < 64; off <<= 1) m = fmaxf(m, __shfl_xor(m, off, 64));
            const float p0 = __expf(acc0.x - m), p1 = __expf(acc0.y - m);
            const float p2 = __expf(acc0.z - m), p3 = __expf(acc0.w - m);
            float s = p0 + p1 + p2 + p3;
            #pragma unroll
            for (int off = 1; off < 64; off <<= 1) s += __shfl_xor(s, off, 64);
            const float sc = 0.25f / s;     // fold mean over H
            *(float4*)&red[h * 512 + 0 * Kc + j4 * 4] =
                make_float4(p0 * sc, p1 * sc, p2 * sc, p3 * sc);
        }
        {
            float m = fmaxf(fmaxf(acc1.x, acc1.y), fmaxf(acc1.z, acc1.w));
            #pragma unroll
            for (int off = 1; off < 64; off <<= 1) m = fmaxf(m, __shfl_xor(m, off, 64));
            const float p0 = __expf(acc1.x - m), p1 = __expf(acc1.y - m);
            const float p2 = __expf(acc1.z - m), p3 = __expf(acc1.w - m);
            float s = p0 + p1 + p2 + p3;
            #pragma unroll
            for (int off = 1; off < 64; off <<= 1) s += __shfl_xor(s, off, 64);
            const float sc = 0.25f / s;
            *(float4*)&red[h * 512 + 1 * Kc + j4 * 4] =
                make_float4(p0 * sc, p1 * sc, p2 * sc, p3 * sc);
        }
    }
    __syncthreads();

    // ---- P-bar = sum over 4 heads ----
    if (tid < 128) {
        const int r = tid >> 6, c = tid & 63;
        float4 s = make_float4(0.f, 0.f, 0.f, 0.f);
        #pragma unroll
        for (int w4 = 0; w4 < 4; ++w4) {
            const float4 v = *(const float4*)&red[w4 * 512 + r * Kc + c * 4];
            s.x += v.x; s.y += v.y; s.z += v.z; s.w += v.w;
        }
        *(float4*)&plbar[r * Kc + c * 4] = s;
    }
    __syncthreads();

    // ---- single PV with P-bar, depth-8 x-load pipeline ----
    const int jq = tid >> 5, dd4 = tid & 31;
    float4 o0 = make_float4(0.f, 0.f, 0.f, 0.f);
    float4 o1 = make_float4(0.f, 0.f, 0.f, 0.f);
    {
        const float* xb = x + (b * Kc) * Dc + dd4 * 4;
        float4 xc[8], xn[8];
        #pragma unroll
        for (int i = 0; i < 8; ++i) xc[i] = *(const float4*)(xb + (i * 8 + jq) * Dc);

        #pragma unroll
        for (int bb = 0; bb < 4; ++bb) {
            #pragma unroll
            for (int i = 0; i < 8; ++i)
                if (bb < 3) xn[i] = *(const float4*)(xb + (((bb + 1) * 8 + i) * 8 + jq) * Dc);
            #pragma unroll
            for (int i = 0; i < 8; ++i) {
                const int j = (bb * 8 + i) * 8 + jq;
                const float4 xv = xc[i];
                const float pv0 = plbar[j];                      // LDS broadcast
                const float pv1 = plbar[Kc + j];
                o0.x = fmaf(pv0, xv.x, o0.x); o0.y = fmaf(pv0, xv.y, o0.y);
                o0.z = fmaf(pv0, xv.z, o0.z); o0.w = fmaf(pv0, xv.w, o0.w);
                o1.x = fmaf(pv1, xv.x, o1.x); o1.y = fmaf(pv1, xv.y, o1.y);
                o1.z = fmaf(pv1, xv.z, o1.z); o1.w = fmaf(pv1, xv.w, o1.w);
            }
            #pragma unroll
            for (int i = 0; i < 8; ++i)
                if (bb < 3) xc[i] = xn[i];
        }
    }
    {
        float* myred = red + (jq * 32 + dd4) * 12;
        *(float4*)&myred[0] = o0;
        *(float4*)&myred[4] = o1;
    }
    __syncthreads();
    if (tid < 64) {
        const int i_f = tid >> 5, dd_f = tid & 31;
        float4 s = make_float4(0.f, 0.f, 0.f, 0.f);
        #pragma unroll
        for (int q = 0; q < 8; ++q) {
            const float4 v = *(const float4*)&red[(q * 32 + dd_f) * 12 + i_f * 4];
            s.x += v.x; s.y += v.y; s.z += v.z; s.w += v.w;
        }
        *(float4*)&out[(b * Kc + i0 + i_f) * Dc + dd_f * 4] = s;
    }
}

extern "C" void kernel_launch(void* const* d_in, const int* in_sizes, int n_in,
                              void* d_out, int out_size, void* d_ws, size_t ws_size,
                              hipStream_t stream) {
    const float* x     = (const float*)d_in[0];
    const float* W     = (const float*)d_in[1];
    const float* lin_b = (const float*)d_in[2];
    const float* a     = (const float*)d_in[3];
    const float* bias  = (const float*)d_in[4];
    float* out = (float*)d_out;

    unsigned int*   Lpp = (unsigned int*)d_ws;                // f16x2 [H][M][64]   (1 MB)
    unsigned int*   Rtp = Lpp + 4 * Mc * 64;                  // f16x2 [16][64][K]  (1 MB)
    float*          eb  = (float*)(Rtp + 16 * 64 * Kc);       // fp32  [16*2][K]    (32 KB)

    k1<<<256, 512, 0, stream>>>(x, W, lin_b, a, Lpp, Rtp, eb);
    k2<<<512, 256, 0, stream>>>(x, a, bias, Lpp, Rtp, eb, out);
}

// Round 18
// 22.603 us; speedup vs baseline: 1.1185x; 1.0120x over previous
//
#include <hip/hip_runtime.h>
#include <math.h>

// B=4, K=256, D=128, H=4, alpha=0.2
// leaky(s) = 0.6*s + 0.4*|s|  (exact for alpha=0.2)
// e_ij = [0.6*(a.Lp_i) cancels in softmax] + 0.6*(a.R_j) + sum_d (0.4 a_d)|Lp_id + R_jd| + bias_ij
// mean_h(P_h @ x) = (mean_h P_h) @ x.
// k1: f16-pair dot2 GEMM (512 thr, 2 waves/SIMD) -> Lpp/Rtp packed f16 + eb.
// k2: 256 blocks x 512 thr, block = (b, 4-row i-tile), wave = (head, i-half);
//     thread owns 2i x 4j over full d (champion inner loop), Rt traffic halved.
constexpr int Kc = 256, Dc = 128, Mc = 1024;    // Mc = B*K

typedef _Float16 h2_t __attribute__((ext_vector_type(2)));
union U32H2 { unsigned int u; h2_t h; };
__device__ inline h2_t u2h(unsigned int u) { U32H2 x; x.u = u; return x.h; }
__device__ inline unsigned int h2u(h2_t h) { U32H2 x; x.h = h; return x.u; }
__device__ inline unsigned int packh(float a, float b) {
    h2_t h; h.x = (_Float16)a; h.y = (_Float16)b; return h2u(h);
}

#if __has_builtin(__builtin_amdgcn_fdot2)
__device__ inline float dot2h(unsigned int a, unsigned int b, float c) {
    return __builtin_amdgcn_fdot2(u2h(a), u2h(b), c, false);
}
#else
__device__ inline float dot2h(unsigned int a, unsigned int b, float c) {
    h2_t ah = u2h(a), bh = u2h(b);
    return fmaf((float)ah.x, (float)bh.x, fmaf((float)ah.y, (float)bh.y, c));
}
#endif

// acc += (0.4a_2d)|l_2d + r_2d| + (0.4a_2d+1)|l_2d+1 + r_2d+1|, f32 accumulate
__device__ inline float estep(unsigned int r, unsigned int l, h2_t av, float acc) {
    h2_t s = u2h(r) + u2h(l);                       // v_pk_add_f16
    unsigned int t = h2u(s) & 0x7FFF7FFFu;          // packed abs
#if __has_builtin(__builtin_amdgcn_fdot2)
    return __builtin_amdgcn_fdot2(u2h(t), av, acc, false);   // v_dot2_f32_f16
#else
    h2_t th = u2h(t);
    return fmaf((float)th.x, (float)av.x, fmaf((float)th.y, (float)av.y, acc));
#endif
}

// ---------------------------------------------------------------------------
// K1 (256 blocks, 512 thr = 8 waves = 2 waves/SIMD): 64x64-tile GEMM,
// 2x4 acc/thread, f16-pair dot2 inner loop.  (byte-identical to R16/R17)
// ---------------------------------------------------------------------------
__global__ __launch_bounds__(512) void k1(const float* __restrict__ x,
                                          const float* __restrict__ W,
                                          const float* __restrict__ lin_b,
                                          const float* __restrict__ a,
                                          unsigned int* __restrict__ Lpp,
                                          unsigned int* __restrict__ Rtp,
                                          float* __restrict__ eb) {
    __shared__ unsigned int As2[64 * 64];   // [k2][m-role] packed k-pairs, 16 KB
    __shared__ unsigned int Bs2[64 * 64];   // [k2][n-role] packed k-pairs, 16 KB
    __shared__ float red[8][16][4];

    const int tid = threadIdx.x;
    const int bid = blockIdx.x;
    const int tx = tid & 15, ty = tid >> 4;   // ty 0..31
    const bool isL = (bid < 128);

    int h, b, m0, n0, dt;
    if (isL) {
        const int nt = bid & 1, mt = (bid >> 1) & 15;
        h = (bid >> 5) & 3; b = 0; dt = 0;
        m0 = mt * 64; n0 = nt * 64;
        {
            const int m_l = tid & 63, kq = tid >> 6;   // kq 0..7
            #pragma unroll
            for (int c = 0; c < 4; ++c) {
                const float4 v = *(const float4*)&x[(m0 + m_l) * Dc + kq * 16 + c * 4];
                As2[(kq * 8 + c * 2 + 0) * 64 + m_l] = packh(v.x, v.y);
                As2[(kq * 8 + c * 2 + 1) * 64 + m_l] = packh(v.z, v.w);
            }
        }
        {
            const int n_l = tid & 63, kq = tid >> 6;
            const float* Wb = W + (h * 2) * Dc * Dc;
            #pragma unroll
            for (int kk = 0; kk < 8; ++kk) {
                const int k2 = kq * 8 + kk;
                Bs2[k2 * 64 + n_l] =
                    packh(Wb[(2 * k2) * Dc + n0 + n_l], Wb[(2 * k2 + 1) * Dc + n0 + n_l]);
            }
        }
    } else {
        const int r_ = bid - 128;
        const int jt = r_ & 3;
        dt = (r_ >> 2) & 1;
        b  = (r_ >> 3) & 3;
        h  = (r_ >> 5) & 3;
        m0 = dt * 64;          // m-role = d
        n0 = jt * 64;          // n-role = j
        {
            const int d_l = tid & 63, kq = tid >> 6;
            const float* Wb = W + ((h * 2 + 1) * Dc) * Dc;
            #pragma unroll
            for (int kk = 0; kk < 8; ++kk) {
                const int k2 = kq * 8 + kk;
                As2[k2 * 64 + d_l] =
                    packh(Wb[(2 * k2) * Dc + m0 + d_l], Wb[(2 * k2 + 1) * Dc + m0 + d_l]);
            }
        }
        {
            const int j_l = tid & 63, kq = tid >> 6;
            #pragma unroll
            for (int c = 0; c < 4; ++c) {
                const float4 v = *(const float4*)&x[(b * Kc + n0 + j_l) * Dc + kq * 16 + c * 4];
                Bs2[(kq * 8 + c * 2 + 0) * 64 + j_l] = packh(v.x, v.y);
                Bs2[(kq * 8 + c * 2 + 1) * 64 + j_l] = packh(v.z, v.w);
            }
        }
    }
    __syncthreads();

    float acc[2][4];
    #pragma unroll
    for (int r = 0; r < 2; ++r)
        #pragma unroll
        for (int c = 0; c < 4; ++c) acc[r][c] = 0.f;

    #pragma unroll 8
    for (int k2 = 0; k2 < 64; ++k2) {
        const uint2 xa = *(const uint2*)&As2[k2 * 64 + ty * 2];   // 2 m x k-pair
        const uint4 wb = *(const uint4*)&Bs2[k2 * 64 + tx * 4];   // 4 n x k-pair
        acc[0][0] = dot2h(xa.x, wb.x, acc[0][0]);
        acc[0][1] = dot2h(xa.x, wb.y, acc[0][1]);
        acc[0][2] = dot2h(xa.x, wb.z, acc[0][2]);
        acc[0][3] = dot2h(xa.x, wb.w, acc[0][3]);
        acc[1][0] = dot2h(xa.y, wb.x, acc[1][0]);
        acc[1][1] = dot2h(xa.y, wb.y, acc[1][1]);
        acc[1][2] = dot2h(xa.y, wb.z, acc[1][2]);
        acc[1][3] = dot2h(xa.y, wb.w, acc[1][3]);
    }

    if (isL) {
        const float4 lv = *(const float4*)&lin_b[h * Dc + n0 + tx * 4];
        #pragma unroll
        for (int r = 0; r < 2; ++r) {
            uint2 pk;
            pk.x = packh(acc[r][0] + lv.x, acc[r][1] + lv.y);
            pk.y = packh(acc[r][2] + lv.z, acc[r][3] + lv.w);
            *(uint2*)&Lpp[(h * Mc + m0 + ty * 2 + r) * 64 + (n0 >> 1) + tx * 2] = pk;
        }
    } else {
        {
            uint4 pk;
            pk.x = packh(acc[0][0], acc[1][0]);
            pk.y = packh(acc[0][1], acc[1][1]);
            pk.z = packh(acc[0][2], acc[1][2]);
            pk.w = packh(acc[0][3], acc[1][3]);
            *(uint4*)&Rtp[((h * 4 + b) * 64 + (m0 >> 1) + ty) * Kc + n0 + tx * 4] = pk;
        }
        const float2 av = *(const float2*)&a[h * Dc + m0 + ty * 2];
        float p0 = 0.4f * (av.x * acc[0][0] + av.y * acc[1][0]);
        float p1 = 0.4f * (av.x * acc[0][1] + av.y * acc[1][1]);
        float p2 = 0.4f * (av.x * acc[0][2] + av.y * acc[1][2]);
        float p3 = 0.4f * (av.x * acc[0][3] + av.y * acc[1][3]);
        p0 += __shfl_xor(p0, 16, 64); p0 += __shfl_xor(p0, 32, 64);
        p1 += __shfl_xor(p1, 16, 64); p1 += __shfl_xor(p1, 32, 64);
        p2 += __shfl_xor(p2, 16, 64); p2 += __shfl_xor(p2, 32, 64);
        p3 += __shfl_xor(p3, 16, 64); p3 += __shfl_xor(p3, 32, 64);
        if (((tid >> 4) & 3) == 0) {
            const int w = tid >> 6;
            red[w][tx][0] = p0; red[w][tx][1] = p1;
            red[w][tx][2] = p2; red[w][tx][3] = p3;
        }
        __syncthreads();
        if (tid < 64) {
            const int txl = tid >> 2, c = tid & 3;
            float v = 0.f;
            #pragma unroll
            for (int w8 = 0; w8 < 8; ++w8) v += red[w8][txl][c];
            eb[((h * 4 + b) * 2 + dt) * Kc + n0 + tid] = 1.5f * v;
        }
    }
}

// ---------------------------------------------------------------------------
// K2 (256 blocks = (b, 64 i-tiles of 4 rows), 512 thr = 8 waves, 65 KB LDS
// -> 2 blk/CU = 16 waves/CU, b pinned per XCD): wave w = (head w>>1,
// i-half w&1); thread owns e[2i][4j] over FULL d=128 — champion's exact
// inner loop, but each Rt plane now shared by 2 waves -> 64 MB total traffic.
// Wave-local softmax (complete rows per wave); P-bar in LDS; single PV -> out.
// ---------------------------------------------------------------------------
#define E4(ACC, LPV)                               \
    ACC.x = estep(rr.x, LPV, av, ACC.x);           \
    ACC.y = estep(rr.y, LPV, av, ACC.y);           \
    ACC.z = estep(rr.z, LPV, av, ACC.z);           \
    ACC.w = estep(rr.w, LPV, av, ACC.w);

__global__ __launch_bounds__(512) void k2(const float* __restrict__ x,
                                          const float* __restrict__ a,
                                          const float* __restrict__ bias,
                                          const unsigned int* __restrict__ Lpp,
                                          const unsigned int* __restrict__ Rtp,
                                          const float* __restrict__ eb,
                                          float* __restrict__ out) {
    __shared__ float red[512 * 20];           // 40 KB PV reduce scratch (16 acc + 4 pad)
    __shared__ float pP[16 * Kc];             // [(h,row)][j] 0.25*P, 16 KB
    __shared__ unsigned int lpT2[4 * 64 * 4]; // [h][dp][i] 4 KB packed-f16 Lp (4 rows)
    __shared__ unsigned int aa2s[4 * 64];     // [h][dp] packed-f16 0.4*a pairs 1 KB
    __shared__ float plbar[4 * Kc];           // fp32 P-bar 4 KB

    const int tid = threadIdx.x;
    const int L = blockIdx.x;
    // XCD-pin: L&7 -> XCD; b = xcd>>1 (2 XCDs per b); it from remaining bits.
    const int xcd = L & 7;
    const int b = xcd >> 1;
    const int it = ((L >> 3) << 1) | (xcd & 1);   // 0..63
    const int i0 = it * 4;

    {   // stage lpT2[h][dp][i] (4 i rows): thread -> (hs = tid>>7, dp = tid&63, ip = (tid>>6)&1)
        const int hs = tid >> 7, dp = tid & 63, ip = (tid >> 6) & 1;
        uint2 v;
        v.x = Lpp[(hs * Mc + b * Kc + i0 + ip * 2 + 0) * 64 + dp];
        v.y = Lpp[(hs * Mc + b * Kc + i0 + ip * 2 + 1) * 64 + dp];
        *(uint2*)&lpT2[(hs * 64 + dp) * 4 + ip * 2] = v;
    }
    if (tid < 256) {
        const int hs = tid >> 6, dp = tid & 63;
        aa2s[tid] = packh(0.4f * a[hs * Dc + 2 * dp], 0.4f * a[hs * Dc + 2 * dp + 1]);
    }
    __syncthreads();

    const int w = tid >> 6;                   // wave 0..7
    const int h = w >> 1, ih = w & 1, j4 = tid & 63;
    const int hb = h * 4 + b;
    const int r0 = ih * 2, r1 = ih * 2 + 1;   // this wave's rows within the 4-row tile

    // hoisted epilogue loads: latency hides under the e-loop
    const float4 ebv0 = *(const float4*)&eb[(hb * 2 + 0) * Kc + j4 * 4];
    const float4 ebv1 = *(const float4*)&eb[(hb * 2 + 1) * Kc + j4 * 4];
    const float4 bv0  = *(const float4*)&bias[(h * Kc + i0 + r0) * Kc + j4 * 4];
    const float4 bv1  = *(const float4*)&bias[(h * Kc + i0 + r1) * Kc + j4 * 4];

    // ---- e-phase: full d in-thread, acc[2 rows][4 j], depth-8 load pipeline ----
    float4 acc0 = make_float4(0.f, 0.f, 0.f, 0.f);
    float4 acc1 = make_float4(0.f, 0.f, 0.f, 0.f);
    {
        const unsigned int* rb = Rtp + (hb * 64) * Kc + j4 * 4;
        const unsigned int* lt = lpT2 + (h * 64) * 4 + r0;   // +r0: row offset within [4]
        const unsigned int* at = aa2s + h * 64;

        uint4 cur[8], nxt[8];
        #pragma unroll
        for (int i = 0; i < 8; ++i) cur[i] = *(const uint4*)(rb + i * Kc);

        #pragma unroll
        for (int bb = 0; bb < 8; ++bb) {
            #pragma unroll
            for (int i = 0; i < 8; ++i)
                if (bb < 7) nxt[i] = *(const uint4*)(rb + ((bb + 1) * 8 + i) * Kc);
            #pragma unroll
            for (int i = 0; i < 8; ++i) {
                const int dp = bb * 8 + i;
                const uint4 rr = cur[i];
                const uint2 lp2 = *(const uint2*)(lt + dp * 4);   // rows r0,r1 (LDS b64)
                const h2_t av = u2h(at[dp]);                      // LDS b32 broadcast
                E4(acc0, lp2.x);
                E4(acc1, lp2.y);
            }
            #pragma unroll
            for (int i = 0; i < 8; ++i)
                if (bb < 7) cur[i] = nxt[i];
        }
    }

    // ---- epilogue + softmax (wave-local, 2 complete rows) ----
    {
        const float jx = ebv0.x + ebv1.x, jy = ebv0.y + ebv1.y;
        const float jz = ebv0.z + ebv1.z, jw = ebv0.w + ebv1.w;
        acc0.x += jx + bv0.x; acc0.y += jy + bv0.y;
        acc0.z += jz + bv0.z; acc0.w += jw + bv0.w;
        acc1.x += jx + bv1.x; acc1.y += jy + bv1.y;
        acc1.z += jz + bv1.z; acc1.w += jw + bv1.w;

        {
            float m = fmaxf(fmaxf(acc0.x, acc0.y), fmaxf(acc0.z, acc0.w));
            #pragma unroll
            for (int off = 1; off < 64; off <<= 1) m = fmaxf(m, __shfl_xor(m, off, 64));
            const float p0 = __expf(acc0.x - m), p1 = __expf(acc0.y - m);
            const float p2 = __expf(acc0.z - m), p3 = __expf(acc0.w - m);
            float s = p0 + p1 + p2 + p3;
            #pragma unroll
            for (int off = 1; off < 64; off <<= 1) s += __shfl_xor(s, off, 64);
            const float sc = 0.25f / s;     // fold mean over H
            *(float4*)&pP[(h * 4 + r0) * Kc + j4 * 4] =
                make_float4(p0 * sc, p1 * sc, p2 * sc, p3 * sc);
        }
        {
            float m = fmaxf(fmaxf(acc1.x, acc1.y), fmaxf(acc1.z, acc1.w));
            #pragma unroll
            for (int off = 1; off < 64; off <<= 1) m = fmaxf(m, __shfl_xor(m, off, 64));
            const float p0 = __expf(acc1.x - m), p1 = __expf(acc1.y - m);
            const float p2 = __expf(acc1.z - m), p3 = __expf(acc1.w - m);
            float s = p0 + p1 + p2 + p3;
            #pragma unroll
            for (int off = 1; off < 64; off <<= 1) s += __shfl_xor(s, off, 64);
            const float sc = 0.25f / s;
            *(float4*)&pP[(h * 4 + r1) * Kc + j4 * 4] =
                make_float4(p0 * sc, p1 * sc, p2 * sc, p3 * sc);
        }
    }
    __syncthreads();

    // ---- P-bar[4][256] = sum over 4 heads ----
    if (tid < 256) {
        const int r = tid >> 6, c = tid & 63;
        float4 s = make_float4(0.f, 0.f, 0.f, 0.f);
        #pragma unroll
        for (int h4 = 0; h4 < 4; ++h4) {
            const float4 v = *(const float4*)&pP[(h4 * 4 + r) * Kc + c * 4];
            s.x += v.x; s.y += v.y; s.z += v.z; s.w += v.w;
        }
        *(float4*)&plbar[r * Kc + c * 4] = s;
    }
    __syncthreads();

    // ---- single PV with P-bar: 16-way jq split, depth-8 x-load pipeline ----
    const int jq = tid >> 5, dd4 = tid & 31;   // jq 0..15
    float4 o0 = make_float4(0.f, 0.f, 0.f, 0.f);
    float4 o1 = make_float4(0.f, 0.f, 0.f, 0.f);
    float4 o2 = make_float4(0.f, 0.f, 0.f, 0.f);
    float4 o3 = make_float4(0.f, 0.f, 0.f, 0.f);
    {
        const float* xb = x + (b * Kc) * Dc + dd4 * 4;
        float4 xc[8], xn[8];
        #pragma unroll
        for (int i = 0; i < 8; ++i) xc[i] = *(const float4*)(xb + (i * 16 + jq) * Dc);

        #pragma unroll
        for (int bb = 0; bb < 2; ++bb) {
            #pragma unroll
            for (int i = 0; i < 8; ++i)
                if (bb < 1) xn[i] = *(const float4*)(xb + (((bb + 1) * 8 + i) * 16 + jq) * Dc);
            #pragma unroll
            for (int i = 0; i < 8; ++i) {
                const int j = (bb * 8 + i) * 16 + jq;
                const float4 xv = xc[i];
                const float pv0 = plbar[0 * Kc + j];
                const float pv1 = plbar[1 * Kc + j];
                const float pv2 = plbar[2 * Kc + j];
                const float pv3 = plbar[3 * Kc + j];
                o0.x = fmaf(pv0, xv.x, o0.x); o0.y = fmaf(pv0, xv.y, o0.y);
                o0.z = fmaf(pv0, xv.z, o0.z); o0.w = fmaf(pv0, xv.w, o0.w);
                o1.x = fmaf(pv1, xv.x, o1.x); o1.y = fmaf(pv1, xv.y, o1.y);
                o1.z = fmaf(pv1, xv.z, o1.z); o1.w = fmaf(pv1, xv.w, o1.w);
                o2.x = fmaf(pv2, xv.x, o2.x); o2.y = fmaf(pv2, xv.y, o2.y);
                o2.z = fmaf(pv2, xv.z, o2.z); o2.w = fmaf(pv2, xv.w, o2.w);
                o3.x = fmaf(pv3, xv.x, o3.x); o3.y = fmaf(pv3, xv.y, o3.y);
                o3.z = fmaf(pv3, xv.z, o3.z); o3.w = fmaf(pv3, xv.w, o3.w);
            }
            #pragma unroll
            for (int i = 0; i < 8; ++i)
                if (bb < 1) xc[i] = xn[i];
        }
    }
    {
        float* myred = red + tid * 20;
        *(float4*)&myred[0]  = o0;
        *(float4*)&myred[4]  = o1;
        *(float4*)&myred[8]  = o2;
        *(float4*)&myred[12] = o3;
    }
    __syncthreads();
    if (tid < 128) {
        const int i_f = tid >> 5, dd_f = tid & 31;   // i_f 0..3
        float4 s = make_float4(0.f, 0.f, 0.f, 0.f);
        #pragma unroll
        for (int q = 0; q < 16; ++q) {
            const float4 v = *(const float4*)&red[(q * 32 + dd_f) * 20 + i_f * 4];
            s.x += v.x; s.y += v.y; s.z += v.z; s.w += v.w;
        }
        *(float4*)&out[(b * Kc + i0 + i_f) * Dc + dd_f * 4] = s;
    }
}

extern "C" void kernel_launch(void* const* d_in, const int* in_sizes, int n_in,
                              void* d_out, int out_size, void* d_ws, size_t ws_size,
                              hipStream_t stream) {
    const float* x     = (const float*)d_in[0];
    const float* W     = (const float*)d_in[1];
    const float* lin_b = (const float*)d_in[2];
    const float* a     = (const float*)d_in[3];
    const float* bias  = (const float*)d_in[4];
    float* out = (float*)d_out;

    unsigned int*   Lpp = (unsigned int*)d_ws;                // f16x2 [H][M][64]   (1 MB)
    unsigned int*   Rtp = Lpp + 4 * Mc * 64;                  // f16x2 [16][64][K]  (1 MB)
    float*          eb  = (float*)(Rtp + 16 * 64 * Kc);       // fp32  [16*2][K]    (32 KB)

    k1<<<256, 512, 0, stream>>>(x, W, lin_b, a, Lpp, Rtp, eb);
    k2<<<256, 512, 0, stream>>>(x, a, bias, Lpp, Rtp, eb, out);
}